// Round 3
// baseline (575.780 us; speedup 1.0000x reference)
//
#include <hip/hip_runtime.h>
#include <cstdint>
#include <cstddef>

#define NNODES 502
#define NKG    500
#define NPAD   512
#define NEDGE  4000
#define NET    4502   // NEDGE + NNODES self loops
#define BB     128
#define DD     1024
#define HH     256
#define MROWS  (BB*NNODES)   // 64256
#define MT     65536         // BB*NPAD padded rows
#define MCAT   628           // NKG + BB rows in hcat

typedef short short8 __attribute__((ext_vector_type(8)));
typedef float f32x4  __attribute__((ext_vector_type(4)));

__device__ __forceinline__ unsigned short f2bf(float f) {
  union { float f; unsigned int u; } v; v.f = f;
  unsigned int r = v.u + 0x7fffu + ((v.u >> 16) & 1u);
  return (unsigned short)(r >> 16);
}

// async global->LDS, 16B per lane; LDS dest = wave-uniform base + lane*16
__device__ __forceinline__ void stage16(const void* g, void* l) {
  __builtin_amdgcn_global_load_lds((__attribute__((address_space(1))) void*)g,
                                   (__attribute__((address_space(3))) void*)l, 16, 0, 0);
}

__device__ __forceinline__ void mfma16(f32x4& c, short8 a, short8 b) {
  asm volatile("v_mfma_f32_16x16x32_bf16 %0, %1, %2, %0" : "+v"(c) : "v"(a), "v"(b));
}

// ---------------- edge helpers ----------------
__device__ inline void get_edge(const int* __restrict__ e, int i, int i64mode,
                                int& src, int& dst) {
  if (i < NEDGE) {
    if (i64mode) { src = e[2*i]; dst = e[2*NEDGE + 2*i]; }
    else         { src = e[i];   dst = e[NEDGE + i]; }
  } else {
    src = dst = i - NEDGE;   // self loop
  }
  src = min(max(src, 0), NNODES-1);
  dst = min(max(dst, 0), NNODES-1);
}

__global__ void detect_kernel(const int* __restrict__ e, int* __restrict__ flag) {
  int v = e[2*threadIdx.x + 1];
  if (v != 0) atomicOr(flag, 1);
}

__global__ void deg_kernel(const int* __restrict__ e, const int* __restrict__ flag,
                           int* __restrict__ deg) {
  int i = blockIdx.x*256 + threadIdx.x;
  if (i >= NET) return;
  int src, dst; get_edge(e, i, *flag == 0, src, dst);
  atomicAdd(&deg[dst], 1);
}

__global__ void scan_kernel(const int* __restrict__ deg, float* __restrict__ dinv,
                            int* __restrict__ rp, int* __restrict__ cursor) {
  __shared__ int s[512];
  int t = threadIdx.x;
  int cnt = (t < NNODES) ? deg[t] : 0;
  s[t] = cnt;
  if (t < NNODES) dinv[t] = rsqrtf((float)cnt);
  __syncthreads();
  for (int off = 1; off < 512; off <<= 1) {
    int v = (t >= off) ? s[t-off] : 0;
    __syncthreads();
    s[t] += v;
    __syncthreads();
  }
  if (t == 0) rp[0] = 0;
  if (t < NNODES) { rp[t+1] = s[t]; cursor[t] = s[t] - cnt; }
}

__global__ void fill_kernel(const int* __restrict__ e, const int* __restrict__ flag,
                            const float* __restrict__ dinv, int* __restrict__ cursor,
                            int* __restrict__ colA, float* __restrict__ valA) {
  int i = blockIdx.x*256 + threadIdx.x;
  if (i >= NET) return;
  int src, dst; get_edge(e, i, *flag == 0, src, dst);
  int pos = atomicAdd(&cursor[dst], 1);
  colA[pos] = src;
  valA[pos] = dinv[src] * dinv[dst];
}

// dense normalized adjacency (fp32 accumulate in d_out scratch, handles dup edges)
__global__ void sdf_kernel(const int* __restrict__ e, const int* __restrict__ flag,
                           const float* __restrict__ dinv, float* __restrict__ Sdf) {
  int i = blockIdx.x*256 + threadIdx.x;
  if (i >= NET) return;
  int src, dst; get_edge(e, i, *flag == 0, src, dst);
  atomicAdd(&Sdf[dst*NPAD + src], dinv[src]*dinv[dst]);
}

__global__ void sdcvt_kernel(const float* __restrict__ Sdf, unsigned short* __restrict__ Sd) {
  int i = blockIdx.x*256 + threadIdx.x;   // 512*512
  Sd[i] = f2bf(Sdf[i]);
}

// W2/W3 [256,256] fp32 -> Wt[n][k] bf16 (transposed), one launch
__global__ void wtc_kernel(const float* __restrict__ W2, const float* __restrict__ W3,
                           unsigned short* __restrict__ Wt2, unsigned short* __restrict__ Wt3) {
  const float* W = blockIdx.y ? W3 : W2;
  unsigned short* Wt = blockIdx.y ? Wt3 : Wt2;
  int n = blockIdx.x, k = threadIdx.x;
  Wt[n*HH + k] = f2bf(W[k*HH + n]);
}

// W1 [1024,256] fp32 -> Wt1[n][k] bf16 transposed
__global__ void wt1_kernel(const float* __restrict__ W1, unsigned short* __restrict__ Wt1) {
  int n = blockIdx.x;
  for (int k = threadIdx.x; k < DD; k += 256)
    Wt1[n*DD + k] = f2bf(W1[(size_t)k*HH + n]);
}

// [base;sensor;0] -> bf16 Xp1 [640,1024]
__global__ void cvtA_kernel(const float* __restrict__ base, const float* __restrict__ sensor,
                            unsigned short* __restrict__ Xp1) {
  int i = blockIdx.x*256 + threadIdx.x;   // over 640*256, 4 elems each
  int r = i >> 8, c = (i & 255) * 4;
  float4 v = make_float4(0.f, 0.f, 0.f, 0.f);
  if (r < NKG) v = *(const float4*)&base[(size_t)r*DD + c];
  else if (r < MCAT) v = *(const float4*)&sensor[(size_t)(r-NKG)*DD + c];
  union { unsigned short u[4]; uint2 d; } p;
  p.u[0]=f2bf(v.x); p.u[1]=f2bf(v.y); p.u[2]=f2bf(v.z); p.u[3]=f2bf(v.w);
  *(uint2*)&Xp1[(size_t)r*DD + c] = p.d;
}

// ---------------- layer-1 MFMA GEMM: hcat[m,n] = sum_k Xp1[m,k]*Wt1[n,k] ----------------
__global__ __launch_bounds__(256) void gemm1m_kernel(
    const unsigned short* __restrict__ Ag,   // [640,1024]
    const unsigned short* __restrict__ Bg,   // [256,1024]
    float* __restrict__ C) {                 // [628,256] fp32
  __shared__ unsigned short As[128*32];
  __shared__ unsigned short Bs[128*32];
  int tid = threadIdx.x;
  int wave = tid >> 6, lane = tid & 63;
  int l15 = lane & 15, quad = lane >> 4;
  int wm = (wave & 1) * 64, wn = (wave >> 1) * 64;
  int row0 = blockIdx.y * 128, col0 = blockIdx.x * 128;
  f32x4 acc[4][4] = {};
  for (int k0 = 0; k0 < DD; k0 += 32) {
#pragma unroll
    for (int q = 0; q < 2; ++q) {
      int c = wave*128 + q*64 + lane;
      stage16(Ag + (size_t)(row0 + (c>>2))*DD + k0 + (c&3)*8, As + c*8);
      stage16(Bg + (size_t)(col0 + (c>>2))*DD + k0 + (c&3)*8, Bs + c*8);
    }
    __syncthreads();
    short8 af[4], bfv[4];
#pragma unroll
    for (int i = 0; i < 4; ++i) {
      af[i]  = *(const short8*)(As + (wm + i*16 + l15)*32 + quad*8);
      bfv[i] = *(const short8*)(Bs + (wn + i*16 + l15)*32 + quad*8);
    }
#pragma unroll
    for (int mi = 0; mi < 4; ++mi)
#pragma unroll
      for (int ni = 0; ni < 4; ++ni)
        mfma16(acc[mi][ni], af[mi], bfv[ni]);
    __syncthreads();
  }
  asm volatile("s_nop 7\n\ts_nop 7" ::);
#pragma unroll
  for (int ni = 0; ni < 4; ++ni) {
    int n = col0 + wn + ni*16 + l15;
#pragma unroll
    for (int mi = 0; mi < 4; ++mi) {
      int m = row0 + wm + mi*16 + quad*4;
#pragma unroll
      for (int r = 0; r < 4; ++r)
        if (m + r < MCAT) C[(size_t)(m+r)*HH + n] = acc[mi][ni][r];
    }
  }
}

// layer-1 decomposition: A[n,h] over shared srcs, c[n] = coeff of sensor row
__global__ void ac_kernel(const int* __restrict__ rp, const int* __restrict__ colA,
                          const float* __restrict__ valA, const float* __restrict__ hcat,
                          float* __restrict__ Abuf, float* __restrict__ cbuf) {
  int n = blockIdx.x, h = threadIdx.x;
  int s = rp[n], e = rp[n+1];
  float acc = 0.f, cacc = 0.f;
  for (int t = s; t < e; ++t) {
    int cl = colA[t]; float v = valA[t];
    if (cl < NKG) acc += v * hcat[cl*HH + h];
    else if (cl == NKG) cacc += v;
  }
  Abuf[n*HH + h] = acc;
  if (h == 0) cbuf[n] = cacc;
}

__global__ void bn1_kernel(const float* __restrict__ Abuf, const float* __restrict__ cbuf,
                           const float* __restrict__ hcat, const float* __restrict__ gamma,
                           const float* __restrict__ beta, float* __restrict__ scale,
                           float* __restrict__ shift) {
  int h = threadIdx.x;
  float sA = 0, sAA = 0, sAc = 0, sc = 0, scc = 0;
  for (int n = 0; n < NNODES; ++n) {
    float a = Abuf[n*HH + h]; float cn = cbuf[n];
    sA += a; sAA += a*a; sAc += a*cn; sc += cn; scc += cn*cn;
  }
  float ss = 0, sss = 0;
  for (int b = 0; b < BB; ++b) {
    float v = hcat[(NKG + b)*HH + h]; ss += v; sss += v*v;
  }
  const float cnt = (float)MROWS;
  float mean = ((float)BB * sA + sc*ss) / cnt;
  float msq  = ((float)BB * sAA + 2.f*sAc*ss + scc*sss) / cnt;
  float var  = msq - mean*mean;
  float scl  = gamma[h] * rsqrtf(var + 1e-5f);
  scale[h] = scl; shift[h] = beta[h] - mean*scl;
}

// layer-1 output -> padded bf16 Xb [MT,256]; 8 h per thread
__global__ void x2_kernel(const float* __restrict__ Abuf, const float* __restrict__ cbuf,
                          const float* __restrict__ hcat, const float* __restrict__ scale,
                          const float* __restrict__ shift, unsigned short* __restrict__ Xb) {
  int idx = blockIdx.x*256 + threadIdx.x;   // over MT*32
  int row = idx >> 5, h0 = (idx & 31)*8;
  int b = row >> 9, n = row & (NPAD-1);
  union { unsigned short u[8]; uint4 d; } p;
  p.d = make_uint4(0,0,0,0);
  if (n < NNODES) {
    float cn = cbuf[n];
    const float* ap = Abuf + n*HH + h0;
    const float* sp = hcat + (NKG + b)*HH + h0;
    const float* sc = scale + h0; const float* sh = shift + h0;
#pragma unroll
    for (int j = 0; j < 8; ++j) {
      float y = (ap[j] + cn*sp[j])*sc[j] + sh[j];
      y = (y > 0.f) ? y : expm1f(y);
      p.u[j] = f2bf(y);
    }
  }
  *(uint4*)(Xb + (size_t)row*HH + h0) = p.d;
}

// ---------------- MFMA GEMM-T: Tt[n][m] = sum_k Xb[m][k]*Wt[n][k] ----------------
__global__ __launch_bounds__(256) void gemmT_kernel(
    const unsigned short* __restrict__ Ag,   // Xb [MT,256]
    const unsigned short* __restrict__ Bg,   // Wt [256,256] (n-major)
    unsigned short* __restrict__ Tt) {       // [256, MT]
  __shared__ unsigned short As[128*32];
  __shared__ unsigned short Bs[128*32];
  int tid = threadIdx.x;
  int wave = tid >> 6, lane = tid & 63;
  int l15 = lane & 15, quad = lane >> 4;
  int wm = (wave & 1) * 64, wn = (wave >> 1) * 64;
  int row0 = blockIdx.y * 128, col0 = blockIdx.x * 128;
  f32x4 acc[4][4] = {};
  for (int k0 = 0; k0 < HH; k0 += 32) {
#pragma unroll
    for (int q = 0; q < 2; ++q) {
      int c = wave*128 + q*64 + lane;
      stage16(Ag + (size_t)(row0 + (c>>2))*HH + k0 + (c&3)*8, As + c*8);
      stage16(Bg + (size_t)(col0 + (c>>2))*HH + k0 + (c&3)*8, Bs + c*8);
    }
    __syncthreads();
    short8 af[4], bfv[4];
#pragma unroll
    for (int i = 0; i < 4; ++i) {
      af[i]  = *(const short8*)(As + (wm + i*16 + l15)*32 + quad*8);
      bfv[i] = *(const short8*)(Bs + (wn + i*16 + l15)*32 + quad*8);
    }
#pragma unroll
    for (int mi = 0; mi < 4; ++mi)
#pragma unroll
      for (int ni = 0; ni < 4; ++ni)
        mfma16(acc[mi][ni], af[mi], bfv[ni]);
    __syncthreads();
  }
  asm volatile("s_nop 7\n\ts_nop 7" ::);
#pragma unroll
  for (int ni = 0; ni < 4; ++ni) {
    int n = col0 + wn + ni*16 + l15;
#pragma unroll
    for (int mi = 0; mi < 4; ++mi) {
      int m = row0 + wm + mi*16 + quad*4;
      union { unsigned short u[4]; uint2 v; } p;
#pragma unroll
      for (int r = 0; r < 4; ++r) p.u[r] = f2bf(acc[mi][ni][r]);
      *(uint2*)(Tt + (size_t)n*MT + m) = p.v;
    }
  }
}

// ---------------- MFMA GEMM-S: O_b[node][n] = sum_k Sd[node][k]*Tt[n][b*512+k] ----
__global__ __launch_bounds__(256) void gemmS_kernel(
    const unsigned short* __restrict__ Sd,   // [512,512]
    const unsigned short* __restrict__ Tt,   // [256, MT]
    float* __restrict__ O,                   // d_out [B,502,256]
    float* __restrict__ sums, float* __restrict__ ssqs) {
  __shared__ unsigned short As[128*32];
  __shared__ unsigned short Bs[128*32];
  int tid = threadIdx.x;
  int wave = tid >> 6, lane = tid & 63;
  int l15 = lane & 15, quad = lane >> 4;
  int wm = (wave & 1) * 64, wn = (wave >> 1) * 64;
  int row0 = blockIdx.y * 128, col0 = blockIdx.x * 128;
  int b = blockIdx.z;
  f32x4 acc[4][4] = {};
  for (int k0 = 0; k0 < NPAD; k0 += 32) {
#pragma unroll
    for (int q = 0; q < 2; ++q) {
      int c = wave*128 + q*64 + lane;
      stage16(Sd + (size_t)(row0 + (c>>2))*NPAD + k0 + (c&3)*8, As + c*8);
      stage16(Tt + (size_t)(col0 + (c>>2))*MT + b*NPAD + k0 + (c&3)*8, Bs + c*8);
    }
    __syncthreads();
    short8 af[4], bfv[4];
#pragma unroll
    for (int i = 0; i < 4; ++i) {
      af[i]  = *(const short8*)(As + (wm + i*16 + l15)*32 + quad*8);
      bfv[i] = *(const short8*)(Bs + (wn + i*16 + l15)*32 + quad*8);
    }
#pragma unroll
    for (int mi = 0; mi < 4; ++mi)
#pragma unroll
      for (int ni = 0; ni < 4; ++ni)
        mfma16(acc[mi][ni], af[mi], bfv[ni]);
    __syncthreads();
  }
  asm volatile("s_nop 7\n\ts_nop 7" ::);
  float* Ob = O + (size_t)b*NNODES*HH;
  float ps[4] = {0,0,0,0}, pq[4] = {0,0,0,0};
#pragma unroll
  for (int ni = 0; ni < 4; ++ni) {
    int n = col0 + wn + ni*16 + l15;
#pragma unroll
    for (int mi = 0; mi < 4; ++mi) {
      int node = row0 + wm + mi*16 + quad*4;
#pragma unroll
      for (int r = 0; r < 4; ++r) {
        float v = acc[mi][ni][r];
        if (node + r < NNODES) Ob[(size_t)(node+r)*HH + n] = v;
        ps[ni] += v; pq[ni] += v*v;   // pad rows are exactly 0
      }
    }
  }
  __syncthreads();
  float* red = (float*)As;
  red[tid] = 0.f;
  __syncthreads();
#pragma unroll
  for (int ni = 0; ni < 4; ++ni) {
    int cl = wn + ni*16 + l15;
    atomicAdd(&red[cl], ps[ni]);
    atomicAdd(&red[128+cl], pq[ni]);
  }
  __syncthreads();
  if (tid < 128) atomicAdd(&sums[col0+tid], red[tid]);
  else atomicAdd(&ssqs[col0+tid-128], red[tid]);
}

__global__ void finalize_kernel(const float* __restrict__ sums, const float* __restrict__ ssqs,
                                const float* __restrict__ gamma, const float* __restrict__ beta,
                                float* __restrict__ scale, float* __restrict__ shift) {
  int h = threadIdx.x;
  const float cnt = (float)MROWS;
  float mean = sums[h] / cnt;
  float var  = ssqs[h] / cnt - mean*mean;
  float scl  = gamma[h] * rsqrtf(var + 1e-5f);
  scale[h] = scl; shift[h] = beta[h] - mean*scl;
}

// BN+ELU, O fp32 -> Xb bf16 padded; 8 h per thread
__global__ void bnxb_kernel(const float* __restrict__ O, const float* __restrict__ scale,
                            const float* __restrict__ shift, unsigned short* __restrict__ Xb) {
  int idx = blockIdx.x*256 + threadIdx.x;   // over MT*32
  int row = idx >> 5, h0 = (idx & 31)*8;
  int b = row >> 9, n = row & (NPAD-1);
  union { unsigned short u[8]; uint4 d; } p;
  p.d = make_uint4(0,0,0,0);
  if (n < NNODES) {
    const float* sp = O + ((size_t)(b*NNODES + n)*HH + h0);
    const float* sc = scale + h0; const float* sh = shift + h0;
#pragma unroll
    for (int j = 0; j < 8; ++j) {
      float y = sp[j]*sc[j] + sh[j];
      y = (y > 0.f) ? y : expm1f(y);
      p.u[j] = f2bf(y);
    }
  }
  *(uint4*)(Xb + (size_t)row*HH + h0) = p.d;
}

// final BN+ELU in place on d_out fp32
__global__ void bnout_kernel(float* __restrict__ O, const float* __restrict__ scale,
                             const float* __restrict__ shift) {
  int i = blockIdx.x*256 + threadIdx.x;   // over MROWS*64
  int h0 = (i & 63)*4;
  float4 v = *(float4*)(O + (size_t)i*4);
  float y0 = v.x*scale[h0]   + shift[h0];
  float y1 = v.y*scale[h0+1] + shift[h0+1];
  float y2 = v.z*scale[h0+2] + shift[h0+2];
  float y3 = v.w*scale[h0+3] + shift[h0+3];
  v.x = (y0 > 0.f) ? y0 : expm1f(y0);
  v.y = (y1 > 0.f) ? y1 : expm1f(y1);
  v.z = (y2 > 0.f) ? y2 : expm1f(y2);
  v.w = (y3 > 0.f) ? y3 : expm1f(y3);
  *(float4*)(O + (size_t)i*4) = v;
}

extern "C" void kernel_launch(void* const* d_in, const int* in_sizes, int n_in,
                              void* d_out, int out_size, void* d_ws, size_t ws_size,
                              hipStream_t stream) {
  const float* sensor = (const float*)d_in[0];
  const float* base   = (const float*)d_in[1];
  const int*   eidx   = (const int*)d_in[2];
  const float* W1 = (const float*)d_in[3];
  const float* g1 = (const float*)d_in[5];
  const float* be1= (const float*)d_in[6];
  const float* W2 = (const float*)d_in[7];
  const float* g2 = (const float*)d_in[9];
  const float* be2= (const float*)d_in[10];
  const float* W3 = (const float*)d_in[11];
  const float* g3 = (const float*)d_in[13];
  const float* be3= (const float*)d_in[14];

  char* ws = (char*)d_ws;
  int*   deg    = (int*)(ws + 0);          // zeroed
  float* sum2   = (float*)(ws + 2048);     // zeroed
  float* ssq2   = (float*)(ws + 3072);     // zeroed
  float* sum3   = (float*)(ws + 4096);     // zeroed
  float* ssq3   = (float*)(ws + 5120);     // zeroed
  float* cbuf   = (float*)(ws + 6144);
  int*   cursor = (int*)(ws + 8192);
  int*   flag   = (int*)(ws + 10240);      // zeroed
  float* dinv   = (float*)(ws + 12288);
  int*   rp     = (int*)(ws + 14336);
  int*   colA   = (int*)(ws + 16384);
  float* valA   = (float*)(ws + 36864);
  float* scale1 = (float*)(ws + 57344);
  float* shift1 = (float*)(ws + 58368);
  float* scale2 = (float*)(ws + 59392);
  float* shift2 = (float*)(ws + 60416);
  float* scale3 = (float*)(ws + 61440);
  float* shift3 = (float*)(ws + 62464);
  float* Abuf   = (float*)(ws + 63488);                  // 502*256 f32
  float* hcat   = (float*)(ws + 577536);                 // 628*256 f32
  unsigned short* Wt2 = (unsigned short*)(ws + 1220608); // 256*256 bf16
  unsigned short* Wt3 = (unsigned short*)(ws + 1351680);
  unsigned short* Sd  = (unsigned short*)(ws + 1482752); // 512*512 bf16
  unsigned short* Xb  = (unsigned short*)(ws + 2007040); // MT*256 bf16
  unsigned short* Tt  = (unsigned short*)(ws + 35561472UL); // 256*MT bf16
  // Xp1/Wt1 live inside the Tt region: only used before first gemmT writes Tt
  unsigned short* Xp1 = (unsigned short*)(ws + 35561472UL);            // 640*1024 bf16
  unsigned short* Wt1 = (unsigned short*)(ws + 35561472UL + 1310720);  // 256*1024 bf16
  float* out = (float*)d_out;
  float* Sdf = (float*)d_out;   // scratch before layer-2 writes d_out

  hipMemsetAsync(ws, 0, 12288, stream);
  hipMemsetAsync(d_out, 0, NPAD*NPAD*4, stream);
  detect_kernel<<<1, 256, 0, stream>>>(eidx, flag);
  deg_kernel<<<(NET+255)/256, 256, 0, stream>>>(eidx, flag, deg);
  scan_kernel<<<1, 512, 0, stream>>>(deg, dinv, rp, cursor);
  fill_kernel<<<(NET+255)/256, 256, 0, stream>>>(eidx, flag, dinv, cursor, colA, valA);
  sdf_kernel<<<(NET+255)/256, 256, 0, stream>>>(eidx, flag, dinv, Sdf);
  sdcvt_kernel<<<(NPAD*NPAD)/256, 256, 0, stream>>>(Sdf, Sd);
  wtc_kernel<<<dim3(HH,2), HH, 0, stream>>>(W2, W3, Wt2, Wt3);
  wt1_kernel<<<HH, 256, 0, stream>>>(W1, Wt1);
  cvtA_kernel<<<640, 256, 0, stream>>>(base, sensor, Xp1);

  gemm1m_kernel<<<dim3(2, 5), 256, 0, stream>>>(Xp1, Wt1, hcat);
  ac_kernel<<<NNODES, 256, 0, stream>>>(rp, colA, valA, hcat, Abuf, cbuf);
  bn1_kernel<<<1, 256, 0, stream>>>(Abuf, cbuf, hcat, g1, be1, scale1, shift1);
  x2_kernel<<<(MT*32)/256, 256, 0, stream>>>(Abuf, cbuf, hcat, scale1, shift1, Xb);

  gemmT_kernel<<<dim3(2, MT/128), 256, 0, stream>>>(Xb, Wt2, Tt);
  gemmS_kernel<<<dim3(2, 4, BB), 256, 0, stream>>>(Sd, Tt, out, sum2, ssq2);
  finalize_kernel<<<1, 256, 0, stream>>>(sum2, ssq2, g2, be2, scale2, shift2);
  bnxb_kernel<<<(MT*32)/256, 256, 0, stream>>>(out, scale2, shift2, Xb);

  gemmT_kernel<<<dim3(2, MT/128), 256, 0, stream>>>(Xb, Wt3, Tt);
  gemmS_kernel<<<dim3(2, 4, BB), 256, 0, stream>>>(Sd, Tt, out, sum3, ssq3);
  finalize_kernel<<<1, 256, 0, stream>>>(sum3, ssq3, g3, be3, scale3, shift3);
  bnout_kernel<<<(MROWS*64)/256, 256, 0, stream>>>(out, scale3, shift3);
}

// Round 4
// 372.625 us; speedup vs baseline: 1.5452x; 1.5452x over previous
//
#include <hip/hip_runtime.h>
#include <cstdint>
#include <cstddef>

#define NNODES 502
#define NKG    500
#define NPAD   512
#define NEDGE  4000
#define NET    4502   // NEDGE + NNODES self loops
#define BB     128
#define DD     1024
#define HH     256
#define MROWS  (BB*NNODES)   // 64256
#define MT     65536         // BB*NPAD padded rows
#define MCAT   628           // NKG + BB rows in hcat

typedef short short8 __attribute__((ext_vector_type(8)));
typedef float f32x4  __attribute__((ext_vector_type(4)));

__device__ __forceinline__ unsigned short f2bf(float f) {
  union { float f; unsigned int u; } v; v.f = f;
  unsigned int r = v.u + 0x7fffu + ((v.u >> 16) & 1u);
  return (unsigned short)(r >> 16);
}

__device__ __forceinline__ float elu(float y) {
  return (y > 0.f) ? y : (__expf(y) - 1.f);
}

// async global->LDS, 16B per lane; LDS dest = wave-uniform base + lane*16
__device__ __forceinline__ void stage16(const void* g, void* l) {
  __builtin_amdgcn_global_load_lds((__attribute__((address_space(1))) void*)g,
                                   (__attribute__((address_space(3))) void*)l, 16, 0, 0);
}

__device__ __forceinline__ void mfma16(f32x4& c, short8 a, short8 b) {
  asm volatile("v_mfma_f32_16x16x32_bf16 %0, %1, %2, %0" : "+v"(c) : "v"(a), "v"(b));
}

// ---------------- edge helpers ----------------
__device__ inline void get_edge(const int* __restrict__ e, int i, int i64mode,
                                int& src, int& dst) {
  if (i < NEDGE) {
    if (i64mode) { src = e[2*i]; dst = e[2*NEDGE + 2*i]; }
    else         { src = e[i];   dst = e[NEDGE + i]; }
  } else {
    src = dst = i - NEDGE;   // self loop
  }
  src = min(max(src, 0), NNODES-1);
  dst = min(max(dst, 0), NNODES-1);
}

__global__ void detect_kernel(const int* __restrict__ e, int* __restrict__ flag) {
  int v = e[2*threadIdx.x + 1];
  if (v != 0) atomicOr(flag, 1);
}

__global__ void deg_kernel(const int* __restrict__ e, const int* __restrict__ flag,
                           int* __restrict__ deg) {
  int i = blockIdx.x*256 + threadIdx.x;
  if (i >= NET) return;
  int src, dst; get_edge(e, i, *flag == 0, src, dst);
  atomicAdd(&deg[dst], 1);
}

__global__ void scan_kernel(const int* __restrict__ deg, float* __restrict__ dinv,
                            int* __restrict__ rp, int* __restrict__ cursor) {
  __shared__ int s[512];
  int t = threadIdx.x;
  int cnt = (t < NNODES) ? deg[t] : 0;
  s[t] = cnt;
  if (t < NNODES) dinv[t] = rsqrtf((float)cnt);
  __syncthreads();
  for (int off = 1; off < 512; off <<= 1) {
    int v = (t >= off) ? s[t-off] : 0;
    __syncthreads();
    s[t] += v;
    __syncthreads();
  }
  if (t == 0) rp[0] = 0;
  if (t < NNODES) { rp[t+1] = s[t]; cursor[t] = s[t] - cnt; }
}

__global__ void fill_kernel(const int* __restrict__ e, const int* __restrict__ flag,
                            const float* __restrict__ dinv, int* __restrict__ cursor,
                            int* __restrict__ colA, float* __restrict__ valA) {
  int i = blockIdx.x*256 + threadIdx.x;
  if (i >= NET) return;
  int src, dst; get_edge(e, i, *flag == 0, src, dst);
  int pos = atomicAdd(&cursor[dst], 1);
  colA[pos] = src;
  valA[pos] = dinv[src] * dinv[dst];
}

// dense normalized adjacency (fp32 accumulate in d_out scratch, handles dup edges)
__global__ void sdf_kernel(const int* __restrict__ e, const int* __restrict__ flag,
                           const float* __restrict__ dinv, float* __restrict__ Sdf) {
  int i = blockIdx.x*256 + threadIdx.x;
  if (i >= NET) return;
  int src, dst; get_edge(e, i, *flag == 0, src, dst);
  atomicAdd(&Sdf[dst*NPAD + src], dinv[src]*dinv[dst]);
}

__global__ void sdcvt_kernel(const float* __restrict__ Sdf, unsigned short* __restrict__ Sd) {
  int i = blockIdx.x*256 + threadIdx.x;   // 512*512
  Sd[i] = f2bf(Sdf[i]);
}

// W2/W3 [256,256] fp32 -> Wt[n][k] bf16 (transposed), one launch
__global__ void wtc_kernel(const float* __restrict__ W2, const float* __restrict__ W3,
                           unsigned short* __restrict__ Wt2, unsigned short* __restrict__ Wt3) {
  const float* W = blockIdx.y ? W3 : W2;
  unsigned short* Wt = blockIdx.y ? Wt3 : Wt2;
  int n = blockIdx.x, k = threadIdx.x;
  Wt[n*HH + k] = f2bf(W[k*HH + n]);
}

// W1 [1024,256] fp32 -> Wt1[n][k] bf16 transposed
__global__ void wt1_kernel(const float* __restrict__ W1, unsigned short* __restrict__ Wt1) {
  int n = blockIdx.x;
  for (int k = threadIdx.x; k < DD; k += 256)
    Wt1[n*DD + k] = f2bf(W1[(size_t)k*HH + n]);
}

// [base;sensor;0] -> bf16 Xp1 [640,1024]
__global__ void cvtA_kernel(const float* __restrict__ base, const float* __restrict__ sensor,
                            unsigned short* __restrict__ Xp1) {
  int i = blockIdx.x*256 + threadIdx.x;   // over 640*256, 4 elems each
  int r = i >> 8, c = (i & 255) * 4;
  float4 v = make_float4(0.f, 0.f, 0.f, 0.f);
  if (r < NKG) v = *(const float4*)&base[(size_t)r*DD + c];
  else if (r < MCAT) v = *(const float4*)&sensor[(size_t)(r-NKG)*DD + c];
  union { unsigned short u[4]; uint2 d; } p;
  p.u[0]=f2bf(v.x); p.u[1]=f2bf(v.y); p.u[2]=f2bf(v.z); p.u[3]=f2bf(v.w);
  *(uint2*)&Xp1[(size_t)r*DD + c] = p.d;
}

// ---------------- layer-1 MFMA GEMM: hcat[m,n] = sum_k Xp1[m,k]*Wt1[n,k] ----------------
__global__ __launch_bounds__(256) void gemm1m_kernel(
    const unsigned short* __restrict__ Ag,   // [640,1024]
    const unsigned short* __restrict__ Bg,   // [256,1024]
    float* __restrict__ C) {                 // [628,256] fp32
  __shared__ unsigned short As[128*32];
  __shared__ unsigned short Bs[128*32];
  int tid = threadIdx.x;
  int wave = tid >> 6, lane = tid & 63;
  int l15 = lane & 15, quad = lane >> 4;
  int wm = (wave & 1) * 64, wn = (wave >> 1) * 64;
  int row0 = blockIdx.y * 128, col0 = blockIdx.x * 128;
  f32x4 acc[4][4] = {};
  for (int k0 = 0; k0 < DD; k0 += 32) {
#pragma unroll
    for (int q = 0; q < 2; ++q) {
      int c = wave*128 + q*64 + lane;
      stage16(Ag + (size_t)(row0 + (c>>2))*DD + k0 + (c&3)*8, As + c*8);
      stage16(Bg + (size_t)(col0 + (c>>2))*DD + k0 + (c&3)*8, Bs + c*8);
    }
    __syncthreads();
    short8 af[4], bfv[4];
#pragma unroll
    for (int i = 0; i < 4; ++i) {
      af[i]  = *(const short8*)(As + (wm + i*16 + l15)*32 + quad*8);
      bfv[i] = *(const short8*)(Bs + (wn + i*16 + l15)*32 + quad*8);
    }
#pragma unroll
    for (int mi = 0; mi < 4; ++mi)
#pragma unroll
      for (int ni = 0; ni < 4; ++ni)
        mfma16(acc[mi][ni], af[mi], bfv[ni]);
    __syncthreads();
  }
  asm volatile("s_nop 7\n\ts_nop 7" ::);
#pragma unroll
  for (int ni = 0; ni < 4; ++ni) {
    int n = col0 + wn + ni*16 + l15;
#pragma unroll
    for (int mi = 0; mi < 4; ++mi) {
      int m = row0 + wm + mi*16 + quad*4;
#pragma unroll
      for (int r = 0; r < 4; ++r)
        if (m + r < MCAT) C[(size_t)(m+r)*HH + n] = acc[mi][ni][r];
    }
  }
}

// layer-1 decomposition: A[n,h] over shared srcs, c[n] = coeff of sensor row
__global__ void ac_kernel(const int* __restrict__ rp, const int* __restrict__ colA,
                          const float* __restrict__ valA, const float* __restrict__ hcat,
                          float* __restrict__ Abuf, float* __restrict__ cbuf) {
  int n = blockIdx.x, h = threadIdx.x;
  int s = rp[n], e = rp[n+1];
  float acc = 0.f, cacc = 0.f;
  for (int t = s; t < e; ++t) {
    int cl = colA[t]; float v = valA[t];
    if (cl < NKG) acc += v * hcat[cl*HH + h];
    else if (cl == NKG) cacc += v;
  }
  Abuf[n*HH + h] = acc;
  if (h == 0) cbuf[n] = cacc;
}

// analytic BN1 stats, parallel over 4 node-slices x 256 channels
__global__ __launch_bounds__(1024) void bn1_kernel(
    const float* __restrict__ Abuf, const float* __restrict__ cbuf,
    const float* __restrict__ hcat, const float* __restrict__ gamma,
    const float* __restrict__ beta, float* __restrict__ scale,
    float* __restrict__ shift) {
  __shared__ float part[4][5][HH];   // 20 KB
  __shared__ float partB[4][2][HH];  // 8 KB
  int h = threadIdx.x & 255, sl = threadIdx.x >> 8;
  float sA = 0, sAA = 0, sAc = 0, sc = 0, scc = 0;
  for (int n = sl; n < NNODES; n += 4) {
    float a = Abuf[n*HH + h]; float cn = cbuf[n];
    sA += a; sAA += a*a; sAc += a*cn; sc += cn; scc += cn*cn;
  }
  part[sl][0][h]=sA; part[sl][1][h]=sAA; part[sl][2][h]=sAc;
  part[sl][3][h]=sc; part[sl][4][h]=scc;
  float ss = 0, sss = 0;
  for (int b = sl; b < BB; b += 4) {
    float v = hcat[(NKG + b)*HH + h]; ss += v; sss += v*v;
  }
  partB[sl][0][h]=ss; partB[sl][1][h]=sss;
  __syncthreads();
  if (sl == 0) {
    sA  = part[0][0][h]+part[1][0][h]+part[2][0][h]+part[3][0][h];
    sAA = part[0][1][h]+part[1][1][h]+part[2][1][h]+part[3][1][h];
    sAc = part[0][2][h]+part[1][2][h]+part[2][2][h]+part[3][2][h];
    sc  = part[0][3][h]+part[1][3][h]+part[2][3][h]+part[3][3][h];
    scc = part[0][4][h]+part[1][4][h]+part[2][4][h]+part[3][4][h];
    ss  = partB[0][0][h]+partB[1][0][h]+partB[2][0][h]+partB[3][0][h];
    sss = partB[0][1][h]+partB[1][1][h]+partB[2][1][h]+partB[3][1][h];
    const float cnt = (float)MROWS;
    float mean = ((float)BB * sA + sc*ss) / cnt;
    float msq  = ((float)BB * sAA + 2.f*sAc*ss + scc*sss) / cnt;
    float var  = msq - mean*mean;
    float scl  = gamma[h] * rsqrtf(var + 1e-5f);
    scale[h] = scl; shift[h] = beta[h] - mean*scl;
  }
}

// layer-1 output -> padded bf16 Xb [MT,256]; 4 ch/thread, loop-free
__global__ __launch_bounds__(256) void x2_kernel(
    const float* __restrict__ Abuf, const float* __restrict__ cbuf,
    const float* __restrict__ hcat, const float* __restrict__ scale,
    const float* __restrict__ shift, unsigned short* __restrict__ Xb) {
  int idx = blockIdx.x*256 + threadIdx.x;   // over MT*64
  int row = idx >> 6, h0 = (idx & 63)*4;
  int b = row >> 9, n = row & (NPAD-1);
  union { unsigned short u[4]; uint2 d; } p;
  p.d = make_uint2(0,0);
  if (n < NNODES) {
    float4 a  = *(const float4*)(Abuf + n*HH + h0);
    float4 s  = *(const float4*)(hcat + (size_t)(NKG + b)*HH + h0);
    float4 sc = *(const float4*)(scale + h0);
    float4 sh = *(const float4*)(shift + h0);
    float cn = cbuf[n];
    p.u[0] = f2bf(elu((a.x + cn*s.x)*sc.x + sh.x));
    p.u[1] = f2bf(elu((a.y + cn*s.y)*sc.y + sh.y));
    p.u[2] = f2bf(elu((a.z + cn*s.z)*sc.z + sh.z));
    p.u[3] = f2bf(elu((a.w + cn*s.w)*sc.w + sh.w));
  }
  *(uint2*)(Xb + (size_t)row*HH + h0) = p.d;
}

// ---------------- MFMA GEMM-T: Tt[n][m] = sum_k Xb[m][k]*Wt[n][k] ----------------
__global__ __launch_bounds__(256) void gemmT_kernel(
    const unsigned short* __restrict__ Ag,   // Xb [MT,256]
    const unsigned short* __restrict__ Bg,   // Wt [256,256] (n-major)
    unsigned short* __restrict__ Tt) {       // [256, MT]
  __shared__ unsigned short As[128*32];
  __shared__ unsigned short Bs[128*32];
  int tid = threadIdx.x;
  int wave = tid >> 6, lane = tid & 63;
  int l15 = lane & 15, quad = lane >> 4;
  int wm = (wave & 1) * 64, wn = (wave >> 1) * 64;
  int row0 = blockIdx.y * 128, col0 = blockIdx.x * 128;
  f32x4 acc[4][4] = {};
  for (int k0 = 0; k0 < HH; k0 += 32) {
#pragma unroll
    for (int q = 0; q < 2; ++q) {
      int c = wave*128 + q*64 + lane;
      stage16(Ag + (size_t)(row0 + (c>>2))*HH + k0 + (c&3)*8, As + c*8);
      stage16(Bg + (size_t)(col0 + (c>>2))*HH + k0 + (c&3)*8, Bs + c*8);
    }
    __syncthreads();
    short8 af[4], bfv[4];
#pragma unroll
    for (int i = 0; i < 4; ++i) {
      af[i]  = *(const short8*)(As + (wm + i*16 + l15)*32 + quad*8);
      bfv[i] = *(const short8*)(Bs + (wn + i*16 + l15)*32 + quad*8);
    }
#pragma unroll
    for (int mi = 0; mi < 4; ++mi)
#pragma unroll
      for (int ni = 0; ni < 4; ++ni)
        mfma16(acc[mi][ni], af[mi], bfv[ni]);
    __syncthreads();
  }
  asm volatile("s_nop 7\n\ts_nop 7" ::);
#pragma unroll
  for (int ni = 0; ni < 4; ++ni) {
    int n = col0 + wn + ni*16 + l15;
#pragma unroll
    for (int mi = 0; mi < 4; ++mi) {
      int m = row0 + wm + mi*16 + quad*4;
      union { unsigned short u[4]; uint2 v; } p;
#pragma unroll
      for (int r = 0; r < 4; ++r) p.u[r] = f2bf(acc[mi][ni][r]);
      *(uint2*)(Tt + (size_t)n*MT + m) = p.v;
    }
  }
}

// ---------------- MFMA GEMM-S: O_b[node][n] = sum_k Sd[node][k]*Tt[n][b*512+k] ----
__global__ __launch_bounds__(256) void gemmS_kernel(
    const unsigned short* __restrict__ Sd,   // [512,512]
    const unsigned short* __restrict__ Tt,   // [256, MT]
    float* __restrict__ O,                   // d_out [B,502,256]
    float* __restrict__ sums, float* __restrict__ ssqs) {
  __shared__ unsigned short As[128*32];
  __shared__ unsigned short Bs[128*32];
  int tid = threadIdx.x;
  int wave = tid >> 6, lane = tid & 63;
  int l15 = lane & 15, quad = lane >> 4;
  int wm = (wave & 1) * 64, wn = (wave >> 1) * 64;
  int row0 = blockIdx.y * 128, col0 = blockIdx.x * 128;
  int b = blockIdx.z;
  f32x4 acc[4][4] = {};
  for (int k0 = 0; k0 < NPAD; k0 += 32) {
#pragma unroll
    for (int q = 0; q < 2; ++q) {
      int c = wave*128 + q*64 + lane;
      stage16(Sd + (size_t)(row0 + (c>>2))*NPAD + k0 + (c&3)*8, As + c*8);
      stage16(Tt + (size_t)(col0 + (c>>2))*MT + b*NPAD + k0 + (c&3)*8, Bs + c*8);
    }
    __syncthreads();
    short8 af[4], bfv[4];
#pragma unroll
    for (int i = 0; i < 4; ++i) {
      af[i]  = *(const short8*)(As + (wm + i*16 + l15)*32 + quad*8);
      bfv[i] = *(const short8*)(Bs + (wn + i*16 + l15)*32 + quad*8);
    }
#pragma unroll
    for (int mi = 0; mi < 4; ++mi)
#pragma unroll
      for (int ni = 0; ni < 4; ++ni)
        mfma16(acc[mi][ni], af[mi], bfv[ni]);
    __syncthreads();
  }
  asm volatile("s_nop 7\n\ts_nop 7" ::);
  float* Ob = O + (size_t)b*NNODES*HH;
  float ps[4] = {0,0,0,0}, pq[4] = {0,0,0,0};
#pragma unroll
  for (int ni = 0; ni < 4; ++ni) {
    int n = col0 + wn + ni*16 + l15;
#pragma unroll
    for (int mi = 0; mi < 4; ++mi) {
      int node = row0 + wm + mi*16 + quad*4;
#pragma unroll
      for (int r = 0; r < 4; ++r) {
        float v = acc[mi][ni][r];
        if (node + r < NNODES) Ob[(size_t)(node+r)*HH + n] = v;
        ps[ni] += v; pq[ni] += v*v;   // pad rows are exactly 0
      }
    }
  }
  __syncthreads();
  float* red = (float*)As;
  red[tid] = 0.f;
  __syncthreads();
#pragma unroll
  for (int ni = 0; ni < 4; ++ni) {
    int cl = wn + ni*16 + l15;
    atomicAdd(&red[cl], ps[ni]);
    atomicAdd(&red[128+cl], pq[ni]);
  }
  __syncthreads();
  if (tid < 128) atomicAdd(&sums[col0+tid], red[tid]);
  else atomicAdd(&ssqs[col0+tid-128], red[tid]);
}

__global__ void finalize_kernel(const float* __restrict__ sums, const float* __restrict__ ssqs,
                                const float* __restrict__ gamma, const float* __restrict__ beta,
                                float* __restrict__ scale, float* __restrict__ shift) {
  int h = threadIdx.x;
  const float cnt = (float)MROWS;
  float mean = sums[h] / cnt;
  float var  = ssqs[h] / cnt - mean*mean;
  float scl  = gamma[h] * rsqrtf(var + 1e-5f);
  scale[h] = scl; shift[h] = beta[h] - mean*scl;
}

// BN+ELU, O fp32 -> Xb bf16 padded; 4 ch/thread, loop-free
__global__ __launch_bounds__(256) void bnxb_kernel(
    const float* __restrict__ O, const float* __restrict__ scale,
    const float* __restrict__ shift, unsigned short* __restrict__ Xb) {
  int idx = blockIdx.x*256 + threadIdx.x;   // over MT*64
  int row = idx >> 6, h0 = (idx & 63)*4;
  int b = row >> 9, n = row & (NPAD-1);
  union { unsigned short u[4]; uint2 d; } p;
  p.d = make_uint2(0,0);
  if (n < NNODES) {
    float4 v  = *(const float4*)(O + ((size_t)(b*NNODES + n)*HH + h0));
    float4 sc = *(const float4*)(scale + h0);
    float4 sh = *(const float4*)(shift + h0);
    p.u[0] = f2bf(elu(v.x*sc.x + sh.x));
    p.u[1] = f2bf(elu(v.y*sc.y + sh.y));
    p.u[2] = f2bf(elu(v.z*sc.z + sh.z));
    p.u[3] = f2bf(elu(v.w*sc.w + sh.w));
  }
  *(uint2*)(Xb + (size_t)row*HH + h0) = p.d;
}

// final BN+ELU in place on d_out fp32
__global__ __launch_bounds__(256) void bnout_kernel(
    float* __restrict__ O, const float* __restrict__ scale,
    const float* __restrict__ shift) {
  int i = blockIdx.x*256 + threadIdx.x;   // over MROWS*64
  int h0 = (i & 63)*4;
  float4 v = *(float4*)(O + (size_t)i*4);
  float4 sc = *(const float4*)(scale + h0);
  float4 sh = *(const float4*)(shift + h0);
  v.x = elu(v.x*sc.x + sh.x);
  v.y = elu(v.y*sc.y + sh.y);
  v.z = elu(v.z*sc.z + sh.z);
  v.w = elu(v.w*sc.w + sh.w);
  *(float4*)(O + (size_t)i*4) = v;
}

extern "C" void kernel_launch(void* const* d_in, const int* in_sizes, int n_in,
                              void* d_out, int out_size, void* d_ws, size_t ws_size,
                              hipStream_t stream) {
  const float* sensor = (const float*)d_in[0];
  const float* base   = (const float*)d_in[1];
  const int*   eidx   = (const int*)d_in[2];
  const float* W1 = (const float*)d_in[3];
  const float* g1 = (const float*)d_in[5];
  const float* be1= (const float*)d_in[6];
  const float* W2 = (const float*)d_in[7];
  const float* g2 = (const float*)d_in[9];
  const float* be2= (const float*)d_in[10];
  const float* W3 = (const float*)d_in[11];
  const float* g3 = (const float*)d_in[13];
  const float* be3= (const float*)d_in[14];

  char* ws = (char*)d_ws;
  int*   deg    = (int*)(ws + 0);          // zeroed
  float* sum2   = (float*)(ws + 2048);     // zeroed
  float* ssq2   = (float*)(ws + 3072);     // zeroed
  float* sum3   = (float*)(ws + 4096);     // zeroed
  float* ssq3   = (float*)(ws + 5120);     // zeroed
  float* cbuf   = (float*)(ws + 6144);
  int*   cursor = (int*)(ws + 8192);
  int*   flag   = (int*)(ws + 10240);      // zeroed
  float* dinv   = (float*)(ws + 12288);
  int*   rp     = (int*)(ws + 14336);
  int*   colA   = (int*)(ws + 16384);
  float* valA   = (float*)(ws + 36864);
  float* scale1 = (float*)(ws + 57344);
  float* shift1 = (float*)(ws + 58368);
  float* scale2 = (float*)(ws + 59392);
  float* shift2 = (float*)(ws + 60416);
  float* scale3 = (float*)(ws + 61440);
  float* shift3 = (float*)(ws + 62464);
  float* Abuf   = (float*)(ws + 63488);                  // 502*256 f32
  float* hcat   = (float*)(ws + 577536);                 // 628*256 f32
  unsigned short* Wt2 = (unsigned short*)(ws + 1220608); // 256*256 bf16
  unsigned short* Wt3 = (unsigned short*)(ws + 1351680);
  unsigned short* Sd  = (unsigned short*)(ws + 1482752); // 512*512 bf16
  unsigned short* Xb  = (unsigned short*)(ws + 2007040); // MT*256 bf16
  unsigned short* Tt  = (unsigned short*)(ws + 35561472UL); // 256*MT bf16
  // Xp1/Wt1 live inside the Tt region: only used before first gemmT writes Tt
  unsigned short* Xp1 = (unsigned short*)(ws + 35561472UL);            // 640*1024 bf16
  unsigned short* Wt1 = (unsigned short*)(ws + 35561472UL + 1310720);  // 256*1024 bf16
  float* out = (float*)d_out;
  float* Sdf = (float*)d_out;   // scratch before layer-2 writes d_out

  hipMemsetAsync(ws, 0, 12288, stream);
  hipMemsetAsync(d_out, 0, NPAD*NPAD*4, stream);
  detect_kernel<<<1, 256, 0, stream>>>(eidx, flag);
  deg_kernel<<<(NET+255)/256, 256, 0, stream>>>(eidx, flag, deg);
  scan_kernel<<<1, 512, 0, stream>>>(deg, dinv, rp, cursor);
  fill_kernel<<<(NET+255)/256, 256, 0, stream>>>(eidx, flag, dinv, cursor, colA, valA);
  sdf_kernel<<<(NET+255)/256, 256, 0, stream>>>(eidx, flag, dinv, Sdf);
  sdcvt_kernel<<<(NPAD*NPAD)/256, 256, 0, stream>>>(Sdf, Sd);
  wtc_kernel<<<dim3(HH,2), HH, 0, stream>>>(W2, W3, Wt2, Wt3);
  wt1_kernel<<<HH, 256, 0, stream>>>(W1, Wt1);
  cvtA_kernel<<<640, 256, 0, stream>>>(base, sensor, Xp1);

  gemm1m_kernel<<<dim3(2, 5), 256, 0, stream>>>(Xp1, Wt1, hcat);
  ac_kernel<<<NNODES, 256, 0, stream>>>(rp, colA, valA, hcat, Abuf, cbuf);
  bn1_kernel<<<1, 1024, 0, stream>>>(Abuf, cbuf, hcat, g1, be1, scale1, shift1);
  x2_kernel<<<(MT*64)/256, 256, 0, stream>>>(Abuf, cbuf, hcat, scale1, shift1, Xb);

  gemmT_kernel<<<dim3(2, MT/128), 256, 0, stream>>>(Xb, Wt2, Tt);
  gemmS_kernel<<<dim3(2, 4, BB), 256, 0, stream>>>(Sd, Tt, out, sum2, ssq2);
  finalize_kernel<<<1, 256, 0, stream>>>(sum2, ssq2, g2, be2, scale2, shift2);
  bnxb_kernel<<<(MT*64)/256, 256, 0, stream>>>(out, scale2, shift2, Xb);

  gemmT_kernel<<<dim3(2, MT/128), 256, 0, stream>>>(Xb, Wt3, Tt);
  gemmS_kernel<<<dim3(2, 4, BB), 256, 0, stream>>>(Sd, Tt, out, sum3, ssq3);
  finalize_kernel<<<1, 256, 0, stream>>>(sum3, ssq3, g3, be3, scale3, shift3);
  bnout_kernel<<<(MROWS*64)/256, 256, 0, stream>>>(out, scale3, shift3);
}

// Round 5
// 334.534 us; speedup vs baseline: 1.7211x; 1.1139x over previous
//
#include <hip/hip_runtime.h>
#include <cstdint>
#include <cstddef>

#define NNODES 502
#define NKG    500
#define NPAD   512
#define NEDGE  4000
#define NET    4502   // NEDGE + NNODES self loops
#define BB     128
#define DD     1024
#define HH     256
#define MROWS  (BB*NNODES)   // 64256
#define MT     65536         // BB*NPAD padded rows
#define MCAT   628           // NKG + BB rows in hcat

typedef short short8 __attribute__((ext_vector_type(8)));
typedef float f32x4  __attribute__((ext_vector_type(4)));

__device__ __forceinline__ unsigned short f2bf(float f) {
  union { float f; unsigned int u; } v; v.f = f;
  unsigned int r = v.u + 0x7fffu + ((v.u >> 16) & 1u);
  return (unsigned short)(r >> 16);
}

__device__ __forceinline__ float elu(float y) {
  return (y > 0.f) ? y : (__expf(y) - 1.f);
}

// async global->LDS, 16B per lane; LDS dest = wave-uniform base + lane*16
__device__ __forceinline__ void stage16(const void* g, void* l) {
  __builtin_amdgcn_global_load_lds((__attribute__((address_space(1))) void*)g,
                                   (__attribute__((address_space(3))) void*)l, 16, 0, 0);
}

__device__ __forceinline__ void mfma16(f32x4& c, short8 a, short8 b) {
  asm volatile("v_mfma_f32_16x16x32_bf16 %0, %1, %2, %0" : "+v"(c) : "v"(a), "v"(b));
}

// ---------------- edge helpers ----------------
__device__ inline void get_edge(const int* __restrict__ e, int i, int i64mode,
                                int& src, int& dst) {
  if (i < NEDGE) {
    if (i64mode) { src = e[2*i]; dst = e[2*NEDGE + 2*i]; }
    else         { src = e[i];   dst = e[NEDGE + i]; }
  } else {
    src = dst = i - NEDGE;   // self loop
  }
  src = min(max(src, 0), NNODES-1);
  dst = min(max(dst, 0), NNODES-1);
}

__global__ void detect_kernel(const int* __restrict__ e, int* __restrict__ flag) {
  int v = e[2*threadIdx.x + 1];
  if (v != 0) atomicOr(flag, 1);
}

__global__ void deg_kernel(const int* __restrict__ e, const int* __restrict__ flag,
                           int* __restrict__ deg) {
  int i = blockIdx.x*256 + threadIdx.x;
  if (i >= NET) return;
  int src, dst; get_edge(e, i, *flag == 0, src, dst);
  atomicAdd(&deg[dst], 1);
}

__global__ void scan_kernel(const int* __restrict__ deg, float* __restrict__ dinv,
                            int* __restrict__ rp, int* __restrict__ cursor) {
  __shared__ int s[512];
  int t = threadIdx.x;
  int cnt = (t < NNODES) ? deg[t] : 0;
  s[t] = cnt;
  if (t < NNODES) dinv[t] = rsqrtf((float)cnt);
  __syncthreads();
  for (int off = 1; off < 512; off <<= 1) {
    int v = (t >= off) ? s[t-off] : 0;
    __syncthreads();
    s[t] += v;
    __syncthreads();
  }
  if (t == 0) rp[0] = 0;
  if (t < NNODES) { rp[t+1] = s[t]; cursor[t] = s[t] - cnt; }
}

__global__ void fill_kernel(const int* __restrict__ e, const int* __restrict__ flag,
                            const float* __restrict__ dinv, int* __restrict__ cursor,
                            int* __restrict__ colA, float* __restrict__ valA) {
  int i = blockIdx.x*256 + threadIdx.x;
  if (i >= NET) return;
  int src, dst; get_edge(e, i, *flag == 0, src, dst);
  int pos = atomicAdd(&cursor[dst], 1);
  colA[pos] = src;
  valA[pos] = dinv[src] * dinv[dst];
}

// dense normalized adjacency (fp32 accumulate in d_out scratch, handles dup edges)
__global__ void sdf_kernel(const int* __restrict__ e, const int* __restrict__ flag,
                           const float* __restrict__ dinv, float* __restrict__ Sdf) {
  int i = blockIdx.x*256 + threadIdx.x;
  if (i >= NET) return;
  int src, dst; get_edge(e, i, *flag == 0, src, dst);
  atomicAdd(&Sdf[dst*NPAD + src], dinv[src]*dinv[dst]);
}

__global__ void sdcvt_kernel(const float* __restrict__ Sdf, unsigned short* __restrict__ Sd) {
  int i = blockIdx.x*256 + threadIdx.x;   // 512*512
  Sd[i] = f2bf(Sdf[i]);
}

// fused prep: Wt2/Wt3 transpose-cast (blocks 0..511), Wt1 (512..767), Xp1 (768..1407)
__global__ __launch_bounds__(256) void prep_kernel(
    const float* __restrict__ W1, const float* __restrict__ W2, const float* __restrict__ W3,
    const float* __restrict__ base, const float* __restrict__ sensor,
    unsigned short* __restrict__ Wt1, unsigned short* __restrict__ Wt2,
    unsigned short* __restrict__ Wt3, unsigned short* __restrict__ Xp1) {
  int bid = blockIdx.x, tid = threadIdx.x;
  if (bid < 512) {
    const float* W = (bid & 256) ? W3 : W2;
    unsigned short* Wt = (bid & 256) ? Wt3 : Wt2;
    int n = bid & 255;
    Wt[n*HH + tid] = f2bf(W[(size_t)tid*HH + n]);
  } else if (bid < 768) {
    int n = bid - 512;
    for (int k = tid; k < DD; k += 256)
      Wt1[n*DD + k] = f2bf(W1[(size_t)k*HH + n]);
  } else {
    int i = (bid - 768)*256 + tid;   // over 640*256, 4 elems each
    int r = i >> 8, c = (i & 255) * 4;
    float4 v = make_float4(0.f, 0.f, 0.f, 0.f);
    if (r < NKG) v = *(const float4*)&base[(size_t)r*DD + c];
    else if (r < MCAT) v = *(const float4*)&sensor[(size_t)(r-NKG)*DD + c];
    union { unsigned short u[4]; uint2 d; } p;
    p.u[0]=f2bf(v.x); p.u[1]=f2bf(v.y); p.u[2]=f2bf(v.z); p.u[3]=f2bf(v.w);
    *(uint2*)&Xp1[(size_t)r*DD + c] = p.d;
  }
}

// ---------------- layer-1 MFMA GEMM: hcat[m,n] = sum_k Xp1[m,k]*Wt1[n,k] ----------------
__global__ __launch_bounds__(256) void gemm1m_kernel(
    const unsigned short* __restrict__ Ag,   // [640,1024]
    const unsigned short* __restrict__ Bg,   // [256,1024]
    float* __restrict__ C) {                 // [628,256] fp32
  __shared__ unsigned short As[128*32];
  __shared__ unsigned short Bs[128*32];
  int tid = threadIdx.x;
  int wave = tid >> 6, lane = tid & 63;
  int l15 = lane & 15, quad = lane >> 4;
  int wm = (wave & 1) * 64, wn = (wave >> 1) * 64;
  int row0 = blockIdx.y * 128, col0 = blockIdx.x * 128;
  f32x4 acc[4][4] = {};
  for (int k0 = 0; k0 < DD; k0 += 32) {
#pragma unroll
    for (int q = 0; q < 2; ++q) {
      int c = wave*128 + q*64 + lane;
      stage16(Ag + (size_t)(row0 + (c>>2))*DD + k0 + (c&3)*8, As + c*8);
      stage16(Bg + (size_t)(col0 + (c>>2))*DD + k0 + (c&3)*8, Bs + c*8);
    }
    __syncthreads();
    short8 af[4], bfv[4];
#pragma unroll
    for (int i = 0; i < 4; ++i) {
      af[i]  = *(const short8*)(As + (wm + i*16 + l15)*32 + quad*8);
      bfv[i] = *(const short8*)(Bs + (wn + i*16 + l15)*32 + quad*8);
    }
#pragma unroll
    for (int mi = 0; mi < 4; ++mi)
#pragma unroll
      for (int ni = 0; ni < 4; ++ni)
        mfma16(acc[mi][ni], af[mi], bfv[ni]);
    __syncthreads();
  }
  asm volatile("s_nop 7\n\ts_nop 7" ::);
#pragma unroll
  for (int ni = 0; ni < 4; ++ni) {
    int n = col0 + wn + ni*16 + l15;
#pragma unroll
    for (int mi = 0; mi < 4; ++mi) {
      int m = row0 + wm + mi*16 + quad*4;
#pragma unroll
      for (int r = 0; r < 4; ++r)
        if (m + r < MCAT) C[(size_t)(m+r)*HH + n] = acc[mi][ni][r];
    }
  }
}

// layer-1 decomposition: A[n,h] over shared srcs, c[n] = coeff of sensor row
__global__ void ac_kernel(const int* __restrict__ rp, const int* __restrict__ colA,
                          const float* __restrict__ valA, const float* __restrict__ hcat,
                          float* __restrict__ Abuf, float* __restrict__ cbuf) {
  int n = blockIdx.x, h = threadIdx.x;
  int s = rp[n], e = rp[n+1];
  float acc = 0.f, cacc = 0.f;
  for (int t = s; t < e; ++t) {
    int cl = colA[t]; float v = valA[t];
    if (cl < NKG) acc += v * hcat[cl*HH + h];
    else if (cl == NKG) cacc += v;
  }
  Abuf[n*HH + h] = acc;
  if (h == 0) cbuf[n] = cacc;
}

// BN1 stats, stage 1: parallel partial sums. blocks 0..31: nodes; 32..39: sensor rows.
__global__ __launch_bounds__(256) void bn1n_kernel(
    const float* __restrict__ Abuf, const float* __restrict__ cbuf,
    const float* __restrict__ hcat,
    float* __restrict__ sA1, float* __restrict__ sAA1, float* __restrict__ sAc1,
    float* __restrict__ scp, float* __restrict__ ssA, float* __restrict__ sssA) {
  int bid = blockIdx.x, h = threadIdx.x;
  if (bid < 32) {
    int n0 = bid*16, n1 = min(n0+16, NNODES);
    float sA = 0, sAA = 0, sAc = 0, sc = 0, scc = 0;
    for (int n = n0; n < n1; ++n) {
      float a = Abuf[n*HH + h]; float cn = cbuf[n];
      sA += a; sAA += a*a; sAc += a*cn; sc += cn; scc += cn*cn;
    }
    atomicAdd(&sA1[h], sA); atomicAdd(&sAA1[h], sAA); atomicAdd(&sAc1[h], sAc);
    if (h == 0) { atomicAdd(&scp[0], sc); atomicAdd(&scp[1], scc); }
  } else {
    int b0 = (bid-32)*16;
    float ss = 0, sss = 0;
    for (int b = b0; b < b0+16; ++b) {
      float v = hcat[(size_t)(NKG + b)*HH + h]; ss += v; sss += v*v;
    }
    atomicAdd(&ssA[h], ss); atomicAdd(&sssA[h], sss);
  }
}

// BN1 stats, stage 2: analytic mean/var -> scale/shift
__global__ void fin1_kernel(const float* __restrict__ sA1, const float* __restrict__ sAA1,
                            const float* __restrict__ sAc1, const float* __restrict__ scp,
                            const float* __restrict__ ssA, const float* __restrict__ sssA,
                            const float* __restrict__ gamma, const float* __restrict__ beta,
                            float* __restrict__ scale, float* __restrict__ shift) {
  int h = threadIdx.x;
  float sA = sA1[h], sAA = sAA1[h], sAc = sAc1[h];
  float sc = scp[0], scc = scp[1];
  float ss = ssA[h], sss = sssA[h];
  const float cnt = (float)MROWS;
  float mean = ((float)BB * sA + sc*ss) / cnt;
  float msq  = ((float)BB * sAA + 2.f*sAc*ss + scc*sss) / cnt;
  float var  = msq - mean*mean;
  float scl  = gamma[h] * rsqrtf(var + 1e-5f);
  scale[h] = scl; shift[h] = beta[h] - mean*scl;
}

// layer-1 output -> padded bf16 Xb [MT,256]; 4 ch/thread, loop-free
__global__ __launch_bounds__(256) void x2_kernel(
    const float* __restrict__ Abuf, const float* __restrict__ cbuf,
    const float* __restrict__ hcat, const float* __restrict__ scale,
    const float* __restrict__ shift, unsigned short* __restrict__ Xb) {
  int idx = blockIdx.x*256 + threadIdx.x;   // over MT*64
  int row = idx >> 6, h0 = (idx & 63)*4;
  int b = row >> 9, n = row & (NPAD-1);
  union { unsigned short u[4]; uint2 d; } p;
  p.d = make_uint2(0,0);
  if (n < NNODES) {
    float4 a  = *(const float4*)(Abuf + n*HH + h0);
    float4 s  = *(const float4*)(hcat + (size_t)(NKG + b)*HH + h0);
    float4 sc = *(const float4*)(scale + h0);
    float4 sh = *(const float4*)(shift + h0);
    float cn = cbuf[n];
    p.u[0] = f2bf(elu((a.x + cn*s.x)*sc.x + sh.x));
    p.u[1] = f2bf(elu((a.y + cn*s.y)*sc.y + sh.y));
    p.u[2] = f2bf(elu((a.z + cn*s.z)*sc.z + sh.z));
    p.u[3] = f2bf(elu((a.w + cn*s.w)*sc.w + sh.w));
  }
  *(uint2*)(Xb + (size_t)row*HH + h0) = p.d;
}

// ---------------- MFMA GEMM-T: Tt[n][m] = sum_k Xb[m][k]*Wt[n][k] ----------------
__global__ __launch_bounds__(256) void gemmT_kernel(
    const unsigned short* __restrict__ Ag,   // Xb [MT,256]
    const unsigned short* __restrict__ Bg,   // Wt [256,256] (n-major)
    unsigned short* __restrict__ Tt) {       // [256, MT]
  __shared__ unsigned short As[128*32];
  __shared__ unsigned short Bs[128*32];
  int tid = threadIdx.x;
  int wave = tid >> 6, lane = tid & 63;
  int l15 = lane & 15, quad = lane >> 4;
  int wm = (wave & 1) * 64, wn = (wave >> 1) * 64;
  int row0 = blockIdx.y * 128, col0 = blockIdx.x * 128;
  f32x4 acc[4][4] = {};
  for (int k0 = 0; k0 < HH; k0 += 32) {
#pragma unroll
    for (int q = 0; q < 2; ++q) {
      int c = wave*128 + q*64 + lane;
      stage16(Ag + (size_t)(row0 + (c>>2))*HH + k0 + (c&3)*8, As + c*8);
      stage16(Bg + (size_t)(col0 + (c>>2))*HH + k0 + (c&3)*8, Bs + c*8);
    }
    __syncthreads();
    short8 af[4], bfv[4];
#pragma unroll
    for (int i = 0; i < 4; ++i) {
      af[i]  = *(const short8*)(As + (wm + i*16 + l15)*32 + quad*8);
      bfv[i] = *(const short8*)(Bs + (wn + i*16 + l15)*32 + quad*8);
    }
#pragma unroll
    for (int mi = 0; mi < 4; ++mi)
#pragma unroll
      for (int ni = 0; ni < 4; ++ni)
        mfma16(acc[mi][ni], af[mi], bfv[ni]);
    __syncthreads();
  }
  asm volatile("s_nop 7\n\ts_nop 7" ::);
#pragma unroll
  for (int ni = 0; ni < 4; ++ni) {
    int n = col0 + wn + ni*16 + l15;
#pragma unroll
    for (int mi = 0; mi < 4; ++mi) {
      int m = row0 + wm + mi*16 + quad*4;
      union { unsigned short u[4]; uint2 v; } p;
#pragma unroll
      for (int r = 0; r < 4; ++r) p.u[r] = f2bf(acc[mi][ni][r]);
      *(uint2*)(Tt + (size_t)n*MT + m) = p.v;
    }
  }
}

// ---------------- MFMA GEMM-S: O_b[node][n] = sum_k Sd[node][k]*Tt[n][b*512+k] ----
__global__ __launch_bounds__(256) void gemmS_kernel(
    const unsigned short* __restrict__ Sd,   // [512,512]
    const unsigned short* __restrict__ Tt,   // [256, MT]
    float* __restrict__ O,                   // d_out [B,502,256]
    float* __restrict__ sums, float* __restrict__ ssqs) {
  __shared__ unsigned short As[128*32];
  __shared__ unsigned short Bs[128*32];
  int tid = threadIdx.x;
  int wave = tid >> 6, lane = tid & 63;
  int l15 = lane & 15, quad = lane >> 4;
  int wm = (wave & 1) * 64, wn = (wave >> 1) * 64;
  int row0 = blockIdx.y * 128, col0 = blockIdx.x * 128;
  int b = blockIdx.z;
  f32x4 acc[4][4] = {};
  for (int k0 = 0; k0 < NPAD; k0 += 32) {
#pragma unroll
    for (int q = 0; q < 2; ++q) {
      int c = wave*128 + q*64 + lane;
      stage16(Sd + (size_t)(row0 + (c>>2))*NPAD + k0 + (c&3)*8, As + c*8);
      stage16(Tt + (size_t)(col0 + (c>>2))*MT + b*NPAD + k0 + (c&3)*8, Bs + c*8);
    }
    __syncthreads();
    short8 af[4], bfv[4];
#pragma unroll
    for (int i = 0; i < 4; ++i) {
      af[i]  = *(const short8*)(As + (wm + i*16 + l15)*32 + quad*8);
      bfv[i] = *(const short8*)(Bs + (wn + i*16 + l15)*32 + quad*8);
    }
#pragma unroll
    for (int mi = 0; mi < 4; ++mi)
#pragma unroll
      for (int ni = 0; ni < 4; ++ni)
        mfma16(acc[mi][ni], af[mi], bfv[ni]);
    __syncthreads();
  }
  asm volatile("s_nop 7\n\ts_nop 7" ::);
  float* Ob = O + (size_t)b*NNODES*HH;
  float ps[4] = {0,0,0,0}, pq[4] = {0,0,0,0};
#pragma unroll
  for (int ni = 0; ni < 4; ++ni) {
    int n = col0 + wn + ni*16 + l15;
#pragma unroll
    for (int mi = 0; mi < 4; ++mi) {
      int node = row0 + wm + mi*16 + quad*4;
#pragma unroll
      for (int r = 0; r < 4; ++r) {
        float v = acc[mi][ni][r];
        if (node + r < NNODES) Ob[(size_t)(node+r)*HH + n] = v;
        ps[ni] += v; pq[ni] += v*v;   // pad rows are exactly 0
      }
    }
  }
  __syncthreads();
  float* red = (float*)As;
  red[tid] = 0.f;
  __syncthreads();
#pragma unroll
  for (int ni = 0; ni < 4; ++ni) {
    int cl = wn + ni*16 + l15;
    atomicAdd(&red[cl], ps[ni]);
    atomicAdd(&red[128+cl], pq[ni]);
  }
  __syncthreads();
  if (tid < 128) atomicAdd(&sums[col0+tid], red[tid]);
  else atomicAdd(&ssqs[col0+tid-128], red[tid]);
}

__global__ void finalize_kernel(const float* __restrict__ sums, const float* __restrict__ ssqs,
                                const float* __restrict__ gamma, const float* __restrict__ beta,
                                float* __restrict__ scale, float* __restrict__ shift) {
  int h = threadIdx.x;
  const float cnt = (float)MROWS;
  float mean = sums[h] / cnt;
  float var  = ssqs[h] / cnt - mean*mean;
  float scl  = gamma[h] * rsqrtf(var + 1e-5f);
  scale[h] = scl; shift[h] = beta[h] - mean*scl;
}

// BN+ELU, O fp32 -> Xb bf16 padded; 4 ch/thread, loop-free
__global__ __launch_bounds__(256) void bnxb_kernel(
    const float* __restrict__ O, const float* __restrict__ scale,
    const float* __restrict__ shift, unsigned short* __restrict__ Xb) {
  int idx = blockIdx.x*256 + threadIdx.x;   // over MT*64
  int row = idx >> 6, h0 = (idx & 63)*4;
  int b = row >> 9, n = row & (NPAD-1);
  union { unsigned short u[4]; uint2 d; } p;
  p.d = make_uint2(0,0);
  if (n < NNODES) {
    float4 v  = *(const float4*)(O + ((size_t)(b*NNODES + n)*HH + h0));
    float4 sc = *(const float4*)(scale + h0);
    float4 sh = *(const float4*)(shift + h0);
    p.u[0] = f2bf(elu(v.x*sc.x + sh.x));
    p.u[1] = f2bf(elu(v.y*sc.y + sh.y));
    p.u[2] = f2bf(elu(v.z*sc.z + sh.z));
    p.u[3] = f2bf(elu(v.w*sc.w + sh.w));
  }
  *(uint2*)(Xb + (size_t)row*HH + h0) = p.d;
}

// final BN+ELU in place on d_out fp32
__global__ __launch_bounds__(256) void bnout_kernel(
    float* __restrict__ O, const float* __restrict__ scale,
    const float* __restrict__ shift) {
  int i = blockIdx.x*256 + threadIdx.x;   // over MROWS*64
  int h0 = (i & 63)*4;
  float4 v = *(float4*)(O + (size_t)i*4);
  float4 sc = *(const float4*)(scale + h0);
  float4 sh = *(const float4*)(shift + h0);
  v.x = elu(v.x*sc.x + sh.x);
  v.y = elu(v.y*sc.y + sh.y);
  v.z = elu(v.z*sc.z + sh.z);
  v.w = elu(v.w*sc.w + sh.w);
  *(float4*)(O + (size_t)i*4) = v;
}

extern "C" void kernel_launch(void* const* d_in, const int* in_sizes, int n_in,
                              void* d_out, int out_size, void* d_ws, size_t ws_size,
                              hipStream_t stream) {
  const float* sensor = (const float*)d_in[0];
  const float* base   = (const float*)d_in[1];
  const int*   eidx   = (const int*)d_in[2];
  const float* W1 = (const float*)d_in[3];
  const float* g1 = (const float*)d_in[5];
  const float* be1= (const float*)d_in[6];
  const float* W2 = (const float*)d_in[7];
  const float* g2 = (const float*)d_in[9];
  const float* be2= (const float*)d_in[10];
  const float* W3 = (const float*)d_in[11];
  const float* g3 = (const float*)d_in[13];
  const float* be3= (const float*)d_in[14];

  char* ws = (char*)d_ws;
  // ---- zeroed region [0, 16384) ----
  int*   deg    = (int*)(ws + 0);          // 512*4
  float* sum2   = (float*)(ws + 2048);
  float* ssq2   = (float*)(ws + 3072);
  float* sum3   = (float*)(ws + 4096);
  float* ssq3   = (float*)(ws + 5120);
  float* cbuf   = (float*)(ws + 6144);     // 502*4
  int*   cursor = (int*)(ws + 8192);
  int*   flag   = (int*)(ws + 10240);
  float* sA1    = (float*)(ws + 10496);
  float* sAA1   = (float*)(ws + 11520);
  float* sAc1   = (float*)(ws + 12544);
  float* scp    = (float*)(ws + 13568);    // 2 floats
  float* ssA    = (float*)(ws + 13824);
  float* sssA   = (float*)(ws + 14848);
  // ---- end zeroed ----
  float* dinv   = (float*)(ws + 16384);
  int*   rp     = (int*)(ws + 18432);
  int*   colA   = (int*)(ws + 20480);
  float* valA   = (float*)(ws + 40960);
  float* scale1 = (float*)(ws + 61440);
  float* shift1 = (float*)(ws + 62464);
  float* scale2 = (float*)(ws + 63488);
  float* shift2 = (float*)(ws + 64512);
  float* scale3 = (float*)(ws + 65536);
  float* shift3 = (float*)(ws + 66560);
  float* Abuf   = (float*)(ws + 67584);                  // 502*256 f32
  float* hcat   = (float*)(ws + 581632);                 // 628*256 f32
  unsigned short* Wt2 = (unsigned short*)(ws + 1224704); // 256*256 bf16
  unsigned short* Wt3 = (unsigned short*)(ws + 1355776);
  unsigned short* Sd  = (unsigned short*)(ws + 1486848); // 512*512 bf16
  unsigned short* Xb  = (unsigned short*)(ws + 2011136); // MT*256 bf16
  unsigned short* Tt  = (unsigned short*)(ws + 35565568UL); // 256*MT bf16
  // Xp1/Wt1 alias the Tt region: only used before first gemmT writes Tt
  unsigned short* Xp1 = (unsigned short*)(ws + 35565568UL);            // 640*1024
  unsigned short* Wt1 = (unsigned short*)(ws + 35565568UL + 1310720);  // 256*1024
  float* out = (float*)d_out;
  float* Sdf = (float*)d_out;   // scratch before layer-2 writes d_out

  hipMemsetAsync(ws, 0, 16384, stream);
  hipMemsetAsync(d_out, 0, NPAD*NPAD*4, stream);
  detect_kernel<<<1, 256, 0, stream>>>(eidx, flag);
  deg_kernel<<<(NET+255)/256, 256, 0, stream>>>(eidx, flag, deg);
  scan_kernel<<<1, 512, 0, stream>>>(deg, dinv, rp, cursor);
  fill_kernel<<<(NET+255)/256, 256, 0, stream>>>(eidx, flag, dinv, cursor, colA, valA);
  sdf_kernel<<<(NET+255)/256, 256, 0, stream>>>(eidx, flag, dinv, Sdf);
  sdcvt_kernel<<<(NPAD*NPAD)/256, 256, 0, stream>>>(Sdf, Sd);
  prep_kernel<<<1408, 256, 0, stream>>>(W1, W2, W3, base, sensor, Wt1, Wt2, Wt3, Xp1);

  gemm1m_kernel<<<dim3(2, 5), 256, 0, stream>>>(Xp1, Wt1, hcat);
  ac_kernel<<<NNODES, 256, 0, stream>>>(rp, colA, valA, hcat, Abuf, cbuf);
  bn1n_kernel<<<40, 256, 0, stream>>>(Abuf, cbuf, hcat, sA1, sAA1, sAc1, scp, ssA, sssA);
  fin1_kernel<<<1, 256, 0, stream>>>(sA1, sAA1, sAc1, scp, ssA, sssA, g1, be1, scale1, shift1);
  x2_kernel<<<(MT*64)/256, 256, 0, stream>>>(Abuf, cbuf, hcat, scale1, shift1, Xb);

  gemmT_kernel<<<dim3(2, MT/128), 256, 0, stream>>>(Xb, Wt2, Tt);
  gemmS_kernel<<<dim3(2, 4, BB), 256, 0, stream>>>(Sd, Tt, out, sum2, ssq2);
  finalize_kernel<<<1, 256, 0, stream>>>(sum2, ssq2, g2, be2, scale2, shift2);
  bnxb_kernel<<<(MT*64)/256, 256, 0, stream>>>(out, scale2, shift2, Xb);

  gemmT_kernel<<<dim3(2, MT/128), 256, 0, stream>>>(Xb, Wt3, Tt);
  gemmS_kernel<<<dim3(2, 4, BB), 256, 0, stream>>>(Sd, Tt, out, sum3, ssq3);
  finalize_kernel<<<1, 256, 0, stream>>>(sum3, ssq3, g3, be3, scale3, shift3);
  bnout_kernel<<<(MROWS*64)/256, 256, 0, stream>>>(out, scale3, shift3);
}

// Round 6
// 328.833 us; speedup vs baseline: 1.7510x; 1.0173x over previous
//
#include <hip/hip_runtime.h>
#include <cstdint>
#include <cstddef>

#define NNODES 502
#define NKG    500
#define NPAD   512
#define NEDGE  4000
#define NET    4502   // NEDGE + NNODES self loops
#define BB     128
#define DD     1024
#define HH     256
#define MROWS  (BB*NNODES)   // 64256
#define MT     65536         // BB*NPAD padded rows
#define MCAT   628           // NKG + BB rows in hcat

typedef short short8 __attribute__((ext_vector_type(8)));
typedef float f32x4  __attribute__((ext_vector_type(4)));

__device__ __forceinline__ unsigned short f2bf(float f) {
  union { float f; unsigned int u; } v; v.f = f;
  unsigned int r = v.u + 0x7fffu + ((v.u >> 16) & 1u);
  return (unsigned short)(r >> 16);
}

__device__ __forceinline__ float bf2f(unsigned short u) {
  union { unsigned int u; float f; } v; v.u = ((unsigned int)u) << 16;
  return v.f;
}

__device__ __forceinline__ float elu(float y) {
  return (y > 0.f) ? y : (__expf(y) - 1.f);
}

// async global->LDS, 16B per lane; LDS dest = wave-uniform base + lane*16
__device__ __forceinline__ void stage16(const void* g, void* l) {
  __builtin_amdgcn_global_load_lds((__attribute__((address_space(1))) void*)g,
                                   (__attribute__((address_space(3))) void*)l, 16, 0, 0);
}

__device__ __forceinline__ void mfma16(f32x4& c, short8 a, short8 b) {
  asm volatile("v_mfma_f32_16x16x32_bf16 %0, %1, %2, %0" : "+v"(c) : "v"(a), "v"(b));
}

// ---------------- edge helpers ----------------
__device__ inline void get_edge(const int* __restrict__ e, int i, int i64mode,
                                int& src, int& dst) {
  if (i < NEDGE) {
    if (i64mode) { src = e[2*i]; dst = e[2*NEDGE + 2*i]; }
    else         { src = e[i];   dst = e[NEDGE + i]; }
  } else {
    src = dst = i - NEDGE;   // self loop
  }
  src = min(max(src, 0), NNODES-1);
  dst = min(max(dst, 0), NNODES-1);
}

__global__ void detect_kernel(const int* __restrict__ e, int* __restrict__ flag) {
  int v = e[2*threadIdx.x + 1];
  if (v != 0) atomicOr(flag, 1);
}

__global__ void deg_kernel(const int* __restrict__ e, const int* __restrict__ flag,
                           int* __restrict__ deg) {
  int i = blockIdx.x*256 + threadIdx.x;
  if (i >= NET) return;
  int src, dst; get_edge(e, i, *flag == 0, src, dst);
  atomicAdd(&deg[dst], 1);
}

__global__ void scan_kernel(const int* __restrict__ deg, float* __restrict__ dinv,
                            int* __restrict__ rp, int* __restrict__ cursor) {
  __shared__ int s[512];
  int t = threadIdx.x;
  int cnt = (t < NNODES) ? deg[t] : 0;
  s[t] = cnt;
  if (t < NNODES) dinv[t] = rsqrtf((float)cnt);
  __syncthreads();
  for (int off = 1; off < 512; off <<= 1) {
    int v = (t >= off) ? s[t-off] : 0;
    __syncthreads();
    s[t] += v;
    __syncthreads();
  }
  if (t == 0) rp[0] = 0;
  if (t < NNODES) { rp[t+1] = s[t]; cursor[t] = s[t] - cnt; }
}

__global__ void fill_kernel(const int* __restrict__ e, const int* __restrict__ flag,
                            const float* __restrict__ dinv, int* __restrict__ cursor,
                            int* __restrict__ colA, float* __restrict__ valA) {
  int i = blockIdx.x*256 + threadIdx.x;
  if (i >= NET) return;
  int src, dst; get_edge(e, i, *flag == 0, src, dst);
  int pos = atomicAdd(&cursor[dst], 1);
  colA[pos] = src;
  valA[pos] = dinv[src] * dinv[dst];
}

// dense normalized adjacency (fp32 accumulate in d_out scratch, handles dup edges)
__global__ void sdf_kernel(const int* __restrict__ e, const int* __restrict__ flag,
                           const float* __restrict__ dinv, float* __restrict__ Sdf) {
  int i = blockIdx.x*256 + threadIdx.x;
  if (i >= NET) return;
  int src, dst; get_edge(e, i, *flag == 0, src, dst);
  atomicAdd(&Sdf[dst*NPAD + src], dinv[src]*dinv[dst]);
}

__global__ void sdcvt_kernel(const float* __restrict__ Sdf, unsigned short* __restrict__ Sd) {
  int i = blockIdx.x*256 + threadIdx.x;   // 512*512
  Sd[i] = f2bf(Sdf[i]);
}

// fused prep: Wt2/Wt3 transpose-cast (blocks 0..511), Wt1 (512..767), Xp1 (768..1407)
__global__ __launch_bounds__(256) void prep_kernel(
    const float* __restrict__ W1, const float* __restrict__ W2, const float* __restrict__ W3,
    const float* __restrict__ base, const float* __restrict__ sensor,
    unsigned short* __restrict__ Wt1, unsigned short* __restrict__ Wt2,
    unsigned short* __restrict__ Wt3, unsigned short* __restrict__ Xp1) {
  int bid = blockIdx.x, tid = threadIdx.x;
  if (bid < 512) {
    const float* W = (bid & 256) ? W3 : W2;
    unsigned short* Wt = (bid & 256) ? Wt3 : Wt2;
    int n = bid & 255;
    Wt[n*HH + tid] = f2bf(W[(size_t)tid*HH + n]);
  } else if (bid < 768) {
    int n = bid - 512;
    for (int k = tid; k < DD; k += 256)
      Wt1[n*DD + k] = f2bf(W1[(size_t)k*HH + n]);
  } else {
    int i = (bid - 768)*256 + tid;   // over 640*256, 4 elems each
    int r = i >> 8, c = (i & 255) * 4;
    float4 v = make_float4(0.f, 0.f, 0.f, 0.f);
    if (r < NKG) v = *(const float4*)&base[(size_t)r*DD + c];
    else if (r < MCAT) v = *(const float4*)&sensor[(size_t)(r-NKG)*DD + c];
    union { unsigned short u[4]; uint2 d; } p;
    p.u[0]=f2bf(v.x); p.u[1]=f2bf(v.y); p.u[2]=f2bf(v.z); p.u[3]=f2bf(v.w);
    *(uint2*)&Xp1[(size_t)r*DD + c] = p.d;
  }
}

// ---------------- layer-1 MFMA GEMM: hcat[m,n] = sum_k Xp1[m,k]*Wt1[n,k] ----------------
__global__ __launch_bounds__(256) void gemm1m_kernel(
    const unsigned short* __restrict__ Ag,   // [640,1024]
    const unsigned short* __restrict__ Bg,   // [256,1024]
    float* __restrict__ C) {                 // [628,256] fp32
  __shared__ unsigned short As[128*32];
  __shared__ unsigned short Bs[128*32];
  int tid = threadIdx.x;
  int wave = tid >> 6, lane = tid & 63;
  int l15 = lane & 15, quad = lane >> 4;
  int wm = (wave & 1) * 64, wn = (wave >> 1) * 64;
  int row0 = blockIdx.y * 128, col0 = blockIdx.x * 128;
  f32x4 acc[4][4] = {};
  for (int k0 = 0; k0 < DD; k0 += 32) {
#pragma unroll
    for (int q = 0; q < 2; ++q) {
      int c = wave*128 + q*64 + lane;
      stage16(Ag + (size_t)(row0 + (c>>2))*DD + k0 + (c&3)*8, As + c*8);
      stage16(Bg + (size_t)(col0 + (c>>2))*DD + k0 + (c&3)*8, Bs + c*8);
    }
    __syncthreads();
    short8 af[4], bfv[4];
#pragma unroll
    for (int i = 0; i < 4; ++i) {
      af[i]  = *(const short8*)(As + (wm + i*16 + l15)*32 + quad*8);
      bfv[i] = *(const short8*)(Bs + (wn + i*16 + l15)*32 + quad*8);
    }
#pragma unroll
    for (int mi = 0; mi < 4; ++mi)
#pragma unroll
      for (int ni = 0; ni < 4; ++ni)
        mfma16(acc[mi][ni], af[mi], bfv[ni]);
    __syncthreads();
  }
  asm volatile("s_nop 7\n\ts_nop 7" ::);
#pragma unroll
  for (int ni = 0; ni < 4; ++ni) {
    int n = col0 + wn + ni*16 + l15;
#pragma unroll
    for (int mi = 0; mi < 4; ++mi) {
      int m = row0 + wm + mi*16 + quad*4;
#pragma unroll
      for (int r = 0; r < 4; ++r)
        if (m + r < MCAT) C[(size_t)(m+r)*HH + n] = acc[mi][ni][r];
    }
  }
}

// layer-1 decomposition: A[n,h] over shared srcs, c[n] = coeff of sensor row
__global__ void ac_kernel(const int* __restrict__ rp, const int* __restrict__ colA,
                          const float* __restrict__ valA, const float* __restrict__ hcat,
                          float* __restrict__ Abuf, float* __restrict__ cbuf) {
  int n = blockIdx.x, h = threadIdx.x;
  int s = rp[n], e = rp[n+1];
  float acc = 0.f, cacc = 0.f;
  for (int t = s; t < e; ++t) {
    int cl = colA[t]; float v = valA[t];
    if (cl < NKG) acc += v * hcat[cl*HH + h];
    else if (cl == NKG) cacc += v;
  }
  Abuf[n*HH + h] = acc;
  if (h == 0) cbuf[n] = cacc;
}

// BN1 stats, stage 1: parallel partial sums. blocks 0..31: nodes; 32..39: sensor rows.
__global__ __launch_bounds__(256) void bn1n_kernel(
    const float* __restrict__ Abuf, const float* __restrict__ cbuf,
    const float* __restrict__ hcat,
    float* __restrict__ sA1, float* __restrict__ sAA1, float* __restrict__ sAc1,
    float* __restrict__ scp, float* __restrict__ ssA, float* __restrict__ sssA) {
  int bid = blockIdx.x, h = threadIdx.x;
  if (bid < 32) {
    int n0 = bid*16, n1 = min(n0+16, NNODES);
    float sA = 0, sAA = 0, sAc = 0, sc = 0, scc = 0;
    for (int n = n0; n < n1; ++n) {
      float a = Abuf[n*HH + h]; float cn = cbuf[n];
      sA += a; sAA += a*a; sAc += a*cn; sc += cn; scc += cn*cn;
    }
    atomicAdd(&sA1[h], sA); atomicAdd(&sAA1[h], sAA); atomicAdd(&sAc1[h], sAc);
    if (h == 0) { atomicAdd(&scp[0], sc); atomicAdd(&scp[1], scc); }
  } else {
    int b0 = (bid-32)*16;
    float ss = 0, sss = 0;
    for (int b = b0; b < b0+16; ++b) {
      float v = hcat[(size_t)(NKG + b)*HH + h]; ss += v; sss += v*v;
    }
    atomicAdd(&ssA[h], ss); atomicAdd(&sssA[h], sss);
  }
}

// BN1 stats, stage 2: analytic mean/var -> scale/shift
__global__ void fin1_kernel(const float* __restrict__ sA1, const float* __restrict__ sAA1,
                            const float* __restrict__ sAc1, const float* __restrict__ scp,
                            const float* __restrict__ ssA, const float* __restrict__ sssA,
                            const float* __restrict__ gamma, const float* __restrict__ beta,
                            float* __restrict__ scale, float* __restrict__ shift) {
  int h = threadIdx.x;
  float sA = sA1[h], sAA = sAA1[h], sAc = sAc1[h];
  float sc = scp[0], scc = scp[1];
  float ss = ssA[h], sss = sssA[h];
  const float cnt = (float)MROWS;
  float mean = ((float)BB * sA + sc*ss) / cnt;
  float msq  = ((float)BB * sAA + 2.f*sAc*ss + scc*sss) / cnt;
  float var  = msq - mean*mean;
  float scl  = gamma[h] * rsqrtf(var + 1e-5f);
  scale[h] = scl; shift[h] = beta[h] - mean*scl;
}

// layer-1 output -> padded bf16 Xb [MT,256]; 4 ch/thread, loop-free
__global__ __launch_bounds__(256) void x2_kernel(
    const float* __restrict__ Abuf, const float* __restrict__ cbuf,
    const float* __restrict__ hcat, const float* __restrict__ scale,
    const float* __restrict__ shift, unsigned short* __restrict__ Xb) {
  int idx = blockIdx.x*256 + threadIdx.x;   // over MT*64
  int row = idx >> 6, h0 = (idx & 63)*4;
  int b = row >> 9, n = row & (NPAD-1);
  union { unsigned short u[4]; uint2 d; } p;
  p.d = make_uint2(0,0);
  if (n < NNODES) {
    float4 a  = *(const float4*)(Abuf + n*HH + h0);
    float4 s  = *(const float4*)(hcat + (size_t)(NKG + b)*HH + h0);
    float4 sc = *(const float4*)(scale + h0);
    float4 sh = *(const float4*)(shift + h0);
    float cn = cbuf[n];
    p.u[0] = f2bf(elu((a.x + cn*s.x)*sc.x + sh.x));
    p.u[1] = f2bf(elu((a.y + cn*s.y)*sc.y + sh.y));
    p.u[2] = f2bf(elu((a.z + cn*s.z)*sc.z + sh.z));
    p.u[3] = f2bf(elu((a.w + cn*s.w)*sc.w + sh.w));
  }
  *(uint2*)(Xb + (size_t)row*HH + h0) = p.d;
}

// ---------------- MFMA GEMM-T: Tt[n][m] = sum_k Xb[m][k]*Wt[n][k] ----------------
__global__ __launch_bounds__(256) void gemmT_kernel(
    const unsigned short* __restrict__ Ag,   // Xb [MT,256]
    const unsigned short* __restrict__ Bg,   // Wt [256,256] (n-major)
    unsigned short* __restrict__ Tt) {       // [256, MT]
  __shared__ unsigned short As[128*32];
  __shared__ unsigned short Bs[128*32];
  int tid = threadIdx.x;
  int wave = tid >> 6, lane = tid & 63;
  int l15 = lane & 15, quad = lane >> 4;
  int wm = (wave & 1) * 64, wn = (wave >> 1) * 64;
  int row0 = blockIdx.y * 128, col0 = blockIdx.x * 128;
  f32x4 acc[4][4] = {};
  for (int k0 = 0; k0 < HH; k0 += 32) {
#pragma unroll
    for (int q = 0; q < 2; ++q) {
      int c = wave*128 + q*64 + lane;
      stage16(Ag + (size_t)(row0 + (c>>2))*HH + k0 + (c&3)*8, As + c*8);
      stage16(Bg + (size_t)(col0 + (c>>2))*HH + k0 + (c&3)*8, Bs + c*8);
    }
    __syncthreads();
    short8 af[4], bfv[4];
#pragma unroll
    for (int i = 0; i < 4; ++i) {
      af[i]  = *(const short8*)(As + (wm + i*16 + l15)*32 + quad*8);
      bfv[i] = *(const short8*)(Bs + (wn + i*16 + l15)*32 + quad*8);
    }
#pragma unroll
    for (int mi = 0; mi < 4; ++mi)
#pragma unroll
      for (int ni = 0; ni < 4; ++ni)
        mfma16(acc[mi][ni], af[mi], bfv[ni]);
    __syncthreads();
  }
  asm volatile("s_nop 7\n\ts_nop 7" ::);
#pragma unroll
  for (int ni = 0; ni < 4; ++ni) {
    int n = col0 + wn + ni*16 + l15;
#pragma unroll
    for (int mi = 0; mi < 4; ++mi) {
      int m = row0 + wm + mi*16 + quad*4;
      union { unsigned short u[4]; uint2 v; } p;
#pragma unroll
      for (int r = 0; r < 4; ++r) p.u[r] = f2bf(acc[mi][ni][r]);
      *(uint2*)(Tt + (size_t)n*MT + m) = p.v;
    }
  }
}

// ---------------- MFMA GEMM-S: Xbo[b*512+node][n] = bf16(sum_k Sd[node][k]*Tt[n][b*512+k])
// XCD-swizzled 1D grid (1024 blocks); BN stats from fp32 acc.
__global__ __launch_bounds__(256) void gemmS_kernel(
    const unsigned short* __restrict__ Sd,   // [512,512]
    const unsigned short* __restrict__ Tt,   // [256, MT]
    unsigned short* __restrict__ Xbo,        // [MT,256] bf16 (pads untouched)
    float* __restrict__ sums, float* __restrict__ ssqs) {
  __shared__ unsigned short As[128*32];
  __shared__ unsigned short Bs[128*32];
  int tid = threadIdx.x;
  int wave = tid >> 6, lane = tid & 63;
  int l15 = lane & 15, quad = lane >> 4;
  int wm = (wave & 1) * 64, wn = (wave >> 1) * 64;
  // swizzle: the 4 row-tile blocks sharing one Tt strip land on the same XCD
  int id = blockIdx.x;
  int xcd = id & 7;
  int w = id >> 3;
  int y = w & 3;
  int g = (w >> 2) * 8 + xcd;    // 0..255
  int x = g >> 7;                // col tile (2)
  int b = g & 127;               // batch
  int row0 = y * 128, col0 = x * 128;
  f32x4 acc[4][4] = {};
  for (int k0 = 0; k0 < NPAD; k0 += 32) {
#pragma unroll
    for (int q = 0; q < 2; ++q) {
      int c = wave*128 + q*64 + lane;
      stage16(Sd + (size_t)(row0 + (c>>2))*NPAD + k0 + (c&3)*8, As + c*8);
      stage16(Tt + (size_t)(col0 + (c>>2))*MT + b*NPAD + k0 + (c&3)*8, Bs + c*8);
    }
    __syncthreads();
    short8 af[4], bfv[4];
#pragma unroll
    for (int i = 0; i < 4; ++i) {
      af[i]  = *(const short8*)(As + (wm + i*16 + l15)*32 + quad*8);
      bfv[i] = *(const short8*)(Bs + (wn + i*16 + l15)*32 + quad*8);
    }
#pragma unroll
    for (int mi = 0; mi < 4; ++mi)
#pragma unroll
      for (int ni = 0; ni < 4; ++ni)
        mfma16(acc[mi][ni], af[mi], bfv[ni]);
    __syncthreads();
  }
  asm volatile("s_nop 7\n\ts_nop 7" ::);
  unsigned short* Xrow = Xbo + (size_t)b*NPAD*HH;
  float ps[4] = {0,0,0,0}, pq[4] = {0,0,0,0};
#pragma unroll
  for (int ni = 0; ni < 4; ++ni) {
    int n = col0 + wn + ni*16 + l15;
#pragma unroll
    for (int mi = 0; mi < 4; ++mi) {
      int node = row0 + wm + mi*16 + quad*4;
#pragma unroll
      for (int r = 0; r < 4; ++r) {
        float v = acc[mi][ni][r];
        if (node + r < NNODES) Xrow[(size_t)(node+r)*HH + n] = f2bf(v);
        ps[ni] += v; pq[ni] += v*v;   // pad rows are exactly 0
      }
    }
  }
  __syncthreads();
  float* red = (float*)As;
  red[tid] = 0.f;
  __syncthreads();
#pragma unroll
  for (int ni = 0; ni < 4; ++ni) {
    int cl = wn + ni*16 + l15;
    atomicAdd(&red[cl], ps[ni]);
    atomicAdd(&red[128+cl], pq[ni]);
  }
  __syncthreads();
  if (tid < 128) atomicAdd(&sums[col0+tid], red[tid]);
  else atomicAdd(&ssqs[col0+tid-128], red[tid]);
}

__global__ void finalize_kernel(const float* __restrict__ sums, const float* __restrict__ ssqs,
                                const float* __restrict__ gamma, const float* __restrict__ beta,
                                float* __restrict__ scale, float* __restrict__ shift) {
  int h = threadIdx.x;
  const float cnt = (float)MROWS;
  float mean = sums[h] / cnt;
  float var  = ssqs[h] / cnt - mean*mean;
  float scl  = gamma[h] * rsqrtf(var + 1e-5f);
  scale[h] = scl; shift[h] = beta[h] - mean*scl;
}

// in-place BN+ELU on bf16 Xb; pads (zero) left untouched
__global__ __launch_bounds__(256) void bnip_kernel(
    unsigned short* __restrict__ Xb, const float* __restrict__ scale,
    const float* __restrict__ shift) {
  int idx = blockIdx.x*256 + threadIdx.x;   // over MT*64
  int row = idx >> 6, h0 = (idx & 63)*4;
  int n = row & (NPAD-1);
  if (n >= NNODES) return;
  unsigned short* p = Xb + (size_t)row*HH + h0;
  union { unsigned short u[4]; uint2 d; } v;
  v.d = *(uint2*)p;
  float4 sc = *(const float4*)(scale + h0);
  float4 sh = *(const float4*)(shift + h0);
  v.u[0] = f2bf(elu(bf2f(v.u[0])*sc.x + sh.x));
  v.u[1] = f2bf(elu(bf2f(v.u[1])*sc.y + sh.y));
  v.u[2] = f2bf(elu(bf2f(v.u[2])*sc.z + sh.z));
  v.u[3] = f2bf(elu(bf2f(v.u[3])*sc.w + sh.w));
  *(uint2*)p = v.d;
}

// final BN+ELU: read bf16 Xb (raw layer-3 pre-BN), write fp32 d_out
__global__ __launch_bounds__(256) void bnout_kernel(
    const unsigned short* __restrict__ Xb, const float* __restrict__ scale,
    const float* __restrict__ shift, float* __restrict__ O) {
  int idx = blockIdx.x*256 + threadIdx.x;   // over MT*64
  int row = idx >> 6, h0 = (idx & 63)*4;
  int b = row >> 9, n = row & (NPAD-1);
  if (n >= NNODES) return;
  union { unsigned short u[4]; uint2 d; } v;
  v.d = *(const uint2*)(Xb + (size_t)row*HH + h0);
  float4 sc = *(const float4*)(scale + h0);
  float4 sh = *(const float4*)(shift + h0);
  float4 o;
  o.x = elu(bf2f(v.u[0])*sc.x + sh.x);
  o.y = elu(bf2f(v.u[1])*sc.y + sh.y);
  o.z = elu(bf2f(v.u[2])*sc.z + sh.z);
  o.w = elu(bf2f(v.u[3])*sc.w + sh.w);
  *(float4*)(O + ((size_t)(b*NNODES + n)*HH + h0)) = o;
}

extern "C" void kernel_launch(void* const* d_in, const int* in_sizes, int n_in,
                              void* d_out, int out_size, void* d_ws, size_t ws_size,
                              hipStream_t stream) {
  const float* sensor = (const float*)d_in[0];
  const float* base   = (const float*)d_in[1];
  const int*   eidx   = (const int*)d_in[2];
  const float* W1 = (const float*)d_in[3];
  const float* g1 = (const float*)d_in[5];
  const float* be1= (const float*)d_in[6];
  const float* W2 = (const float*)d_in[7];
  const float* g2 = (const float*)d_in[9];
  const float* be2= (const float*)d_in[10];
  const float* W3 = (const float*)d_in[11];
  const float* g3 = (const float*)d_in[13];
  const float* be3= (const float*)d_in[14];

  char* ws = (char*)d_ws;
  // ---- zeroed region [0, 16384) ----
  int*   deg    = (int*)(ws + 0);
  float* sum2   = (float*)(ws + 2048);
  float* ssq2   = (float*)(ws + 3072);
  float* sum3   = (float*)(ws + 4096);
  float* ssq3   = (float*)(ws + 5120);
  float* cbuf   = (float*)(ws + 6144);
  int*   cursor = (int*)(ws + 8192);
  int*   flag   = (int*)(ws + 10240);
  float* sA1    = (float*)(ws + 10496);
  float* sAA1   = (float*)(ws + 11520);
  float* sAc1   = (float*)(ws + 12544);
  float* scp    = (float*)(ws + 13568);
  float* ssA    = (float*)(ws + 13824);
  float* sssA   = (float*)(ws + 14848);
  // ---- end zeroed ----
  float* dinv   = (float*)(ws + 16384);
  int*   rp     = (int*)(ws + 18432);
  int*   colA   = (int*)(ws + 20480);
  float* valA   = (float*)(ws + 40960);
  float* scale1 = (float*)(ws + 61440);
  float* shift1 = (float*)(ws + 62464);
  float* scale2 = (float*)(ws + 63488);
  float* shift2 = (float*)(ws + 64512);
  float* scale3 = (float*)(ws + 65536);
  float* shift3 = (float*)(ws + 66560);
  float* Abuf   = (float*)(ws + 67584);                  // 502*256 f32
  float* hcat   = (float*)(ws + 581632);                 // 628*256 f32
  unsigned short* Wt2 = (unsigned short*)(ws + 1224704); // 256*256 bf16
  unsigned short* Wt3 = (unsigned short*)(ws + 1355776);
  unsigned short* Sd  = (unsigned short*)(ws + 1486848); // 512*512 bf16
  unsigned short* Xb  = (unsigned short*)(ws + 2011136); // MT*256 bf16
  unsigned short* Tt  = (unsigned short*)(ws + 35565568UL); // 256*MT bf16
  // Xp1/Wt1 alias the Tt region: only used before first gemmT writes Tt
  unsigned short* Xp1 = (unsigned short*)(ws + 35565568UL);            // 640*1024
  unsigned short* Wt1 = (unsigned short*)(ws + 35565568UL + 1310720);  // 256*1024
  float* out = (float*)d_out;
  float* Sdf = (float*)d_out;   // scratch; d_out rewritten by bnout at the end

  hipMemsetAsync(ws, 0, 16384, stream);
  hipMemsetAsync(d_out, 0, NPAD*NPAD*4, stream);
  detect_kernel<<<1, 256, 0, stream>>>(eidx, flag);
  deg_kernel<<<(NET+255)/256, 256, 0, stream>>>(eidx, flag, deg);
  scan_kernel<<<1, 512, 0, stream>>>(deg, dinv, rp, cursor);
  fill_kernel<<<(NET+255)/256, 256, 0, stream>>>(eidx, flag, dinv, cursor, colA, valA);
  sdf_kernel<<<(NET+255)/256, 256, 0, stream>>>(eidx, flag, dinv, Sdf);
  sdcvt_kernel<<<(NPAD*NPAD)/256, 256, 0, stream>>>(Sdf, Sd);
  prep_kernel<<<1408, 256, 0, stream>>>(W1, W2, W3, base, sensor, Wt1, Wt2, Wt3, Xp1);

  gemm1m_kernel<<<dim3(2, 5), 256, 0, stream>>>(Xp1, Wt1, hcat);
  ac_kernel<<<NNODES, 256, 0, stream>>>(rp, colA, valA, hcat, Abuf, cbuf);
  bn1n_kernel<<<40, 256, 0, stream>>>(Abuf, cbuf, hcat, sA1, sAA1, sAc1, scp, ssA, sssA);
  fin1_kernel<<<1, 256, 0, stream>>>(sA1, sAA1, sAc1, scp, ssA, sssA, g1, be1, scale1, shift1);
  x2_kernel<<<(MT*64)/256, 256, 0, stream>>>(Abuf, cbuf, hcat, scale1, shift1, Xb);

  gemmT_kernel<<<dim3(2, MT/128), 256, 0, stream>>>(Xb, Wt2, Tt);
  gemmS_kernel<<<1024, 256, 0, stream>>>(Sd, Tt, Xb, sum2, ssq2);
  finalize_kernel<<<1, 256, 0, stream>>>(sum2, ssq2, g2, be2, scale2, shift2);
  bnip_kernel<<<(MT*64)/256, 256, 0, stream>>>(Xb, scale2, shift2);

  gemmT_kernel<<<dim3(2, MT/128), 256, 0, stream>>>(Xb, Wt3, Tt);
  gemmS_kernel<<<1024, 256, 0, stream>>>(Sd, Tt, Xb, sum3, ssq3);
  finalize_kernel<<<1, 256, 0, stream>>>(sum3, ssq3, g3, be3, scale3, shift3);
  bnout_kernel<<<(MT*64)/256, 256, 0, stream>>>(Xb, scale3, shift3, out);
}

// Round 7
// 325.851 us; speedup vs baseline: 1.7670x; 1.0092x over previous
//
#include <hip/hip_runtime.h>
#include <cstdint>
#include <cstddef>

#define NNODES 502
#define NKG    500
#define NPAD   512
#define NEDGE  4000
#define NET    4502   // NEDGE + NNODES self loops
#define BB     128
#define DD     1024
#define HH     256
#define MROWS  (BB*NNODES)   // 64256
#define MT     65536         // BB*NPAD padded rows
#define MCAT   628           // NKG + BB rows in hcat
#define EPITCH 136           // padded bf16 row stride for epilogue transpose

typedef short short8 __attribute__((ext_vector_type(8)));
typedef float f32x4  __attribute__((ext_vector_type(4)));

__device__ __forceinline__ unsigned short f2bf(float f) {
  union { float f; unsigned int u; } v; v.f = f;
  unsigned int r = v.u + 0x7fffu + ((v.u >> 16) & 1u);
  return (unsigned short)(r >> 16);
}

__device__ __forceinline__ float bf2f(unsigned short u) {
  union { unsigned int u; float f; } v; v.u = ((unsigned int)u) << 16;
  return v.f;
}

__device__ __forceinline__ float elu(float y) {
  return (y > 0.f) ? y : (__expf(y) - 1.f);
}

// async global->LDS, 16B per lane; LDS dest = wave-uniform base + lane*16
__device__ __forceinline__ void stage16(const void* g, void* l) {
  __builtin_amdgcn_global_load_lds((__attribute__((address_space(1))) void*)g,
                                   (__attribute__((address_space(3))) void*)l, 16, 0, 0);
}

__device__ __forceinline__ void mfma16(f32x4& c, short8 a, short8 b) {
  asm volatile("v_mfma_f32_16x16x32_bf16 %0, %1, %2, %0" : "+v"(c) : "v"(a), "v"(b));
}

// ---------------- edge helpers ----------------
__device__ inline void get_edge(const int* __restrict__ e, int i, int i64mode,
                                int& src, int& dst) {
  if (i < NEDGE) {
    if (i64mode) { src = e[2*i]; dst = e[2*NEDGE + 2*i]; }
    else         { src = e[i];   dst = e[NEDGE + i]; }
  } else {
    src = dst = i - NEDGE;   // self loop
  }
  src = min(max(src, 0), NNODES-1);
  dst = min(max(dst, 0), NNODES-1);
}

__global__ void detect_kernel(const int* __restrict__ e, int* __restrict__ flag) {
  int v = e[2*threadIdx.x + 1];
  if (v != 0) atomicOr(flag, 1);
}

__global__ void deg_kernel(const int* __restrict__ e, const int* __restrict__ flag,
                           int* __restrict__ deg) {
  int i = blockIdx.x*256 + threadIdx.x;
  if (i >= NET) return;
  int src, dst; get_edge(e, i, *flag == 0, src, dst);
  atomicAdd(&deg[dst], 1);
}

__global__ void scan_kernel(const int* __restrict__ deg, float* __restrict__ dinv,
                            int* __restrict__ rp, int* __restrict__ cursor) {
  __shared__ int s[512];
  int t = threadIdx.x;
  int cnt = (t < NNODES) ? deg[t] : 0;
  s[t] = cnt;
  if (t < NNODES) dinv[t] = rsqrtf((float)cnt);
  __syncthreads();
  for (int off = 1; off < 512; off <<= 1) {
    int v = (t >= off) ? s[t-off] : 0;
    __syncthreads();
    s[t] += v;
    __syncthreads();
  }
  if (t == 0) rp[0] = 0;
  if (t < NNODES) { rp[t+1] = s[t]; cursor[t] = s[t] - cnt; }
}

__global__ void fill_kernel(const int* __restrict__ e, const int* __restrict__ flag,
                            const float* __restrict__ dinv, int* __restrict__ cursor,
                            int* __restrict__ colA, float* __restrict__ valA) {
  int i = blockIdx.x*256 + threadIdx.x;
  if (i >= NET) return;
  int src, dst; get_edge(e, i, *flag == 0, src, dst);
  int pos = atomicAdd(&cursor[dst], 1);
  colA[pos] = src;
  valA[pos] = dinv[src] * dinv[dst];
}

// dense normalized adjacency (fp32 accumulate in d_out scratch, handles dup edges)
__global__ void sdf_kernel(const int* __restrict__ e, const int* __restrict__ flag,
                           const float* __restrict__ dinv, float* __restrict__ Sdf) {
  int i = blockIdx.x*256 + threadIdx.x;
  if (i >= NET) return;
  int src, dst; get_edge(e, i, *flag == 0, src, dst);
  atomicAdd(&Sdf[dst*NPAD + src], dinv[src]*dinv[dst]);
}

__global__ void sdcvt_kernel(const float* __restrict__ Sdf, unsigned short* __restrict__ Sd) {
  int i = blockIdx.x*256 + threadIdx.x;   // 512*512
  Sd[i] = f2bf(Sdf[i]);
}

// fused prep: Wt2/Wt3 transpose-cast (blocks 0..511), Wt1 (512..767), Xp1 (768..1407)
__global__ __launch_bounds__(256) void prep_kernel(
    const float* __restrict__ W1, const float* __restrict__ W2, const float* __restrict__ W3,
    const float* __restrict__ base, const float* __restrict__ sensor,
    unsigned short* __restrict__ Wt1, unsigned short* __restrict__ Wt2,
    unsigned short* __restrict__ Wt3, unsigned short* __restrict__ Xp1) {
  int bid = blockIdx.x, tid = threadIdx.x;
  if (bid < 512) {
    const float* W = (bid & 256) ? W3 : W2;
    unsigned short* Wt = (bid & 256) ? Wt3 : Wt2;
    int n = bid & 255;
    Wt[n*HH + tid] = f2bf(W[(size_t)tid*HH + n]);
  } else if (bid < 768) {
    int n = bid - 512;
    for (int k = tid; k < DD; k += 256)
      Wt1[n*DD + k] = f2bf(W1[(size_t)k*HH + n]);
  } else {
    int i = (bid - 768)*256 + tid;   // over 640*256, 4 elems each
    int r = i >> 8, c = (i & 255) * 4;
    float4 v = make_float4(0.f, 0.f, 0.f, 0.f);
    if (r < NKG) v = *(const float4*)&base[(size_t)r*DD + c];
    else if (r < MCAT) v = *(const float4*)&sensor[(size_t)(r-NKG)*DD + c];
    union { unsigned short u[4]; uint2 d; } p;
    p.u[0]=f2bf(v.x); p.u[1]=f2bf(v.y); p.u[2]=f2bf(v.z); p.u[3]=f2bf(v.w);
    *(uint2*)&Xp1[(size_t)r*DD + c] = p.d;
  }
}

// ---------------- layer-1 MFMA GEMM: hcat[m,n] = sum_k Xp1[m,k]*Wt1[n,k] ----------------
__global__ __launch_bounds__(256) void gemm1m_kernel(
    const unsigned short* __restrict__ Ag,   // [640,1024]
    const unsigned short* __restrict__ Bg,   // [256,1024]
    float* __restrict__ C) {                 // [628,256] fp32
  __shared__ unsigned short As[128*32];
  __shared__ unsigned short Bs[128*32];
  int tid = threadIdx.x;
  int wave = tid >> 6, lane = tid & 63;
  int l15 = lane & 15, quad = lane >> 4;
  int wm = (wave & 1) * 64, wn = (wave >> 1) * 64;
  int row0 = blockIdx.y * 128, col0 = blockIdx.x * 128;
  f32x4 acc[4][4] = {};
  for (int k0 = 0; k0 < DD; k0 += 32) {
#pragma unroll
    for (int q = 0; q < 2; ++q) {
      int c = wave*128 + q*64 + lane;
      stage16(Ag + (size_t)(row0 + (c>>2))*DD + k0 + (c&3)*8, As + c*8);
      stage16(Bg + (size_t)(col0 + (c>>2))*DD + k0 + (c&3)*8, Bs + c*8);
    }
    __syncthreads();
    short8 af[4], bfv[4];
#pragma unroll
    for (int i = 0; i < 4; ++i) {
      af[i]  = *(const short8*)(As + (wm + i*16 + l15)*32 + quad*8);
      bfv[i] = *(const short8*)(Bs + (wn + i*16 + l15)*32 + quad*8);
    }
#pragma unroll
    for (int mi = 0; mi < 4; ++mi)
#pragma unroll
      for (int ni = 0; ni < 4; ++ni)
        mfma16(acc[mi][ni], af[mi], bfv[ni]);
    __syncthreads();
  }
  asm volatile("s_nop 7\n\ts_nop 7" ::);
#pragma unroll
  for (int ni = 0; ni < 4; ++ni) {
    int n = col0 + wn + ni*16 + l15;
#pragma unroll
    for (int mi = 0; mi < 4; ++mi) {
      int m = row0 + wm + mi*16 + quad*4;
#pragma unroll
      for (int r = 0; r < 4; ++r)
        if (m + r < MCAT) C[(size_t)(m+r)*HH + n] = acc[mi][ni][r];
    }
  }
}

// layer-1 decomposition: A[n,h] over shared srcs, c[n] = coeff of sensor row
__global__ void ac_kernel(const int* __restrict__ rp, const int* __restrict__ colA,
                          const float* __restrict__ valA, const float* __restrict__ hcat,
                          float* __restrict__ Abuf, float* __restrict__ cbuf) {
  int n = blockIdx.x, h = threadIdx.x;
  int s = rp[n], e = rp[n+1];
  float acc = 0.f, cacc = 0.f;
  for (int t = s; t < e; ++t) {
    int cl = colA[t]; float v = valA[t];
    if (cl < NKG) acc += v * hcat[cl*HH + h];
    else if (cl == NKG) cacc += v;
  }
  Abuf[n*HH + h] = acc;
  if (h == 0) cbuf[n] = cacc;
}

// BN1 stats, stage 1: parallel partial sums. blocks 0..31: nodes; 32..39: sensor rows.
__global__ __launch_bounds__(256) void bn1n_kernel(
    const float* __restrict__ Abuf, const float* __restrict__ cbuf,
    const float* __restrict__ hcat,
    float* __restrict__ sA1, float* __restrict__ sAA1, float* __restrict__ sAc1,
    float* __restrict__ scp, float* __restrict__ ssA, float* __restrict__ sssA) {
  int bid = blockIdx.x, h = threadIdx.x;
  if (bid < 32) {
    int n0 = bid*16, n1 = min(n0+16, NNODES);
    float sA = 0, sAA = 0, sAc = 0, sc = 0, scc = 0;
    for (int n = n0; n < n1; ++n) {
      float a = Abuf[n*HH + h]; float cn = cbuf[n];
      sA += a; sAA += a*a; sAc += a*cn; sc += cn; scc += cn*cn;
    }
    atomicAdd(&sA1[h], sA); atomicAdd(&sAA1[h], sAA); atomicAdd(&sAc1[h], sAc);
    if (h == 0) { atomicAdd(&scp[0], sc); atomicAdd(&scp[1], scc); }
  } else {
    int b0 = (bid-32)*16;
    float ss = 0, sss = 0;
    for (int b = b0; b < b0+16; ++b) {
      float v = hcat[(size_t)(NKG + b)*HH + h]; ss += v; sss += v*v;
    }
    atomicAdd(&ssA[h], ss); atomicAdd(&sssA[h], sss);
  }
}

// BN1 stats, stage 2: analytic mean/var -> scale/shift
__global__ void fin1_kernel(const float* __restrict__ sA1, const float* __restrict__ sAA1,
                            const float* __restrict__ sAc1, const float* __restrict__ scp,
                            const float* __restrict__ ssA, const float* __restrict__ sssA,
                            const float* __restrict__ gamma, const float* __restrict__ beta,
                            float* __restrict__ scale, float* __restrict__ shift) {
  int h = threadIdx.x;
  float sA = sA1[h], sAA = sAA1[h], sAc = sAc1[h];
  float sc = scp[0], scc = scp[1];
  float ss = ssA[h], sss = sssA[h];
  const float cnt = (float)MROWS;
  float mean = ((float)BB * sA + sc*ss) / cnt;
  float msq  = ((float)BB * sAA + 2.f*sAc*ss + scc*sss) / cnt;
  float var  = msq - mean*mean;
  float scl  = gamma[h] * rsqrtf(var + 1e-5f);
  scale[h] = scl; shift[h] = beta[h] - mean*scl;
}

// layer-1 output -> padded bf16 Xb [MT,256]; 4 ch/thread, loop-free
__global__ __launch_bounds__(256) void x2_kernel(
    const float* __restrict__ Abuf, const float* __restrict__ cbuf,
    const float* __restrict__ hcat, const float* __restrict__ scale,
    const float* __restrict__ shift, unsigned short* __restrict__ Xb) {
  int idx = blockIdx.x*256 + threadIdx.x;   // over MT*64
  int row = idx >> 6, h0 = (idx & 63)*4;
  int b = row >> 9, n = row & (NPAD-1);
  union { unsigned short u[4]; uint2 d; } p;
  p.d = make_uint2(0,0);
  if (n < NNODES) {
    float4 a  = *(const float4*)(Abuf + n*HH + h0);
    float4 s  = *(const float4*)(hcat + (size_t)(NKG + b)*HH + h0);
    float4 sc = *(const float4*)(scale + h0);
    float4 sh = *(const float4*)(shift + h0);
    float cn = cbuf[n];
    p.u[0] = f2bf(elu((a.x + cn*s.x)*sc.x + sh.x));
    p.u[1] = f2bf(elu((a.y + cn*s.y)*sc.y + sh.y));
    p.u[2] = f2bf(elu((a.z + cn*s.z)*sc.z + sh.z));
    p.u[3] = f2bf(elu((a.w + cn*s.w)*sc.w + sh.w));
  }
  *(uint2*)(Xb + (size_t)row*HH + h0) = p.d;
}

// ---------------- MFMA GEMM-T: Tt[n][m] = sum_k Xb[m][k]*Wt[n][k] ----------------
// BK=64 (two BK=32 planes), transposed coalesced epilogue via LDS.
__global__ __launch_bounds__(256) void gemmT_kernel(
    const unsigned short* __restrict__ Ag,   // Xb [MT,256]
    const unsigned short* __restrict__ Bg,   // Wt [256,256] (n-major)
    unsigned short* __restrict__ Tt) {       // [256, MT]
  __shared__ __align__(16) unsigned short smem[128*EPITCH];  // >= 16384 staging elems
  unsigned short* As = smem;            // [2 planes][128][32]
  unsigned short* Bs = smem + 8192;
  int tid = threadIdx.x;
  int wave = tid >> 6, lane = tid & 63;
  int l15 = lane & 15, quad = lane >> 4;
  int wm = (wave & 1) * 64, wn = (wave >> 1) * 64;
  int row0 = blockIdx.y * 128, col0 = blockIdx.x * 128;
  f32x4 acc[4][4] = {};
  for (int k0 = 0; k0 < HH; k0 += 64) {
#pragma unroll
    for (int q = 0; q < 4; ++q) {
      int c = q*256 + wave*64 + lane;     // 0..1023
      int half = c >> 9, rr = (c >> 2) & 127, j = c & 3;
      stage16(Ag + (size_t)(row0 + rr)*HH + k0 + half*32 + j*8, As + c*8);
      stage16(Bg + (size_t)(col0 + rr)*HH + k0 + half*32 + j*8, Bs + c*8);
    }
    __syncthreads();
#pragma unroll
    for (int kb = 0; kb < 2; ++kb) {
      short8 af[4], bfv[4];
#pragma unroll
      for (int i = 0; i < 4; ++i) {
        af[i]  = *(const short8*)(As + kb*4096 + (wm + i*16 + l15)*32 + quad*8);
        bfv[i] = *(const short8*)(Bs + kb*4096 + (wn + i*16 + l15)*32 + quad*8);
      }
#pragma unroll
      for (int mi = 0; mi < 4; ++mi)
#pragma unroll
        for (int ni = 0; ni < 4; ++ni)
          mfma16(acc[mi][ni], af[mi], bfv[ni]);
    }
    __syncthreads();
  }
  asm volatile("s_nop 7\n\ts_nop 7" ::);
  // transpose: smem[n_local][m_local], n_local-major
#pragma unroll
  for (int ni = 0; ni < 4; ++ni) {
    int nl = wn + ni*16 + l15;
#pragma unroll
    for (int mi = 0; mi < 4; ++mi) {
      int ml = wm + mi*16 + quad*4;
#pragma unroll
      for (int r = 0; r < 4; ++r)
        smem[nl*EPITCH + ml + r] = f2bf(acc[mi][ni][r]);
    }
  }
  __syncthreads();
  int moff = (tid & 15)*8;
#pragma unroll
  for (int j = 0; j < 8; ++j) {
    int nr = (tid >> 4) + j*16;
    uint4 d = *(const uint4*)(smem + nr*EPITCH + moff);
    *(uint4*)(Tt + (size_t)(col0 + nr)*MT + row0 + moff) = d;
  }
}

// ---------------- MFMA GEMM-S: Xbo[b*512+node][n] = bf16(sum_k Sd[node][k]*Tt[n][b*512+k])
// XCD-swizzled 1D grid (1024 blocks); BK=64; transposed epilogue; BN stats from fp32 acc.
__global__ __launch_bounds__(256) void gemmS_kernel(
    const unsigned short* __restrict__ Sd,   // [512,512]
    const unsigned short* __restrict__ Tt,   // [256, MT]
    unsigned short* __restrict__ Xbo,        // [MT,256] bf16 (pads untouched)
    float* __restrict__ sums, float* __restrict__ ssqs) {
  __shared__ __align__(16) unsigned short smem[128*EPITCH];
  unsigned short* As = smem;
  unsigned short* Bs = smem + 8192;
  int tid = threadIdx.x;
  int wave = tid >> 6, lane = tid & 63;
  int l15 = lane & 15, quad = lane >> 4;
  int wm = (wave & 1) * 64, wn = (wave >> 1) * 64;
  // swizzle: the 4 row-tile blocks sharing one Tt strip land on the same XCD
  int id = blockIdx.x;
  int xcd = id & 7;
  int w = id >> 3;
  int y = w & 3;
  int g = (w >> 2) * 8 + xcd;    // 0..255
  int x = g >> 7;                // col tile (2)
  int b = g & 127;               // batch
  int row0 = y * 128, col0 = x * 128;
  f32x4 acc[4][4] = {};
  for (int k0 = 0; k0 < NPAD; k0 += 64) {
#pragma unroll
    for (int q = 0; q < 4; ++q) {
      int c = q*256 + wave*64 + lane;
      int half = c >> 9, rr = (c >> 2) & 127, j = c & 3;
      stage16(Sd + (size_t)(row0 + rr)*NPAD + k0 + half*32 + j*8, As + c*8);
      stage16(Tt + (size_t)(col0 + rr)*MT + b*NPAD + k0 + half*32 + j*8, Bs + c*8);
    }
    __syncthreads();
#pragma unroll
    for (int kb = 0; kb < 2; ++kb) {
      short8 af[4], bfv[4];
#pragma unroll
      for (int i = 0; i < 4; ++i) {
        af[i]  = *(const short8*)(As + kb*4096 + (wm + i*16 + l15)*32 + quad*8);
        bfv[i] = *(const short8*)(Bs + kb*4096 + (wn + i*16 + l15)*32 + quad*8);
      }
#pragma unroll
      for (int mi = 0; mi < 4; ++mi)
#pragma unroll
        for (int ni = 0; ni < 4; ++ni)
          mfma16(acc[mi][ni], af[mi], bfv[ni]);
    }
    __syncthreads();
  }
  asm volatile("s_nop 7\n\ts_nop 7" ::);
  // BN stat partials from fp32 acc (pad rows contribute exactly 0)
  float ps[4] = {0,0,0,0}, pq[4] = {0,0,0,0};
#pragma unroll
  for (int ni = 0; ni < 4; ++ni)
#pragma unroll
    for (int mi = 0; mi < 4; ++mi)
#pragma unroll
      for (int r = 0; r < 4; ++r) {
        float v = acc[mi][ni][r];
        ps[ni] += v; pq[ni] += v*v;
      }
  // transpose: smem[node_local][n_local]
#pragma unroll
  for (int mi = 0; mi < 4; ++mi) {
    int ml = wm + mi*16 + quad*4;
#pragma unroll
    for (int ni = 0; ni < 4; ++ni) {
      int nl = wn + ni*16 + l15;
#pragma unroll
      for (int r = 0; r < 4; ++r)
        smem[(ml + r)*EPITCH + nl] = f2bf(acc[mi][ni][r]);
    }
  }
  __syncthreads();
  unsigned short* Xrow = Xbo + (size_t)b*NPAD*HH;
  int noff = (tid & 15)*8;
#pragma unroll
  for (int j = 0; j < 8; ++j) {
    int rr = (tid >> 4) + j*16;
    int node = row0 + rr;
    if (node < NNODES) {
      uint4 d = *(const uint4*)(smem + rr*EPITCH + noff);
      *(uint4*)(Xrow + (size_t)node*HH + col0 + noff) = d;
    }
  }
  __syncthreads();
  float* red = (float*)smem;
  red[tid] = 0.f;
  __syncthreads();
#pragma unroll
  for (int ni = 0; ni < 4; ++ni) {
    int cl = wn + ni*16 + l15;
    atomicAdd(&red[cl], ps[ni]);
    atomicAdd(&red[128+cl], pq[ni]);
  }
  __syncthreads();
  if (tid < 128) atomicAdd(&sums[col0+tid], red[tid]);
  else atomicAdd(&ssqs[col0+tid-128], red[tid]);
}

__global__ void finalize_kernel(const float* __restrict__ sums, const float* __restrict__ ssqs,
                                const float* __restrict__ gamma, const float* __restrict__ beta,
                                float* __restrict__ scale, float* __restrict__ shift) {
  int h = threadIdx.x;
  const float cnt = (float)MROWS;
  float mean = sums[h] / cnt;
  float var  = ssqs[h] / cnt - mean*mean;
  float scl  = gamma[h] * rsqrtf(var + 1e-5f);
  scale[h] = scl; shift[h] = beta[h] - mean*scl;
}

// in-place BN+ELU on bf16 Xb; pads (zero) left untouched
__global__ __launch_bounds__(256) void bnip_kernel(
    unsigned short* __restrict__ Xb, const float* __restrict__ scale,
    const float* __restrict__ shift) {
  int idx = blockIdx.x*256 + threadIdx.x;   // over MT*64
  int row = idx >> 6, h0 = (idx & 63)*4;
  int n = row & (NPAD-1);
  if (n >= NNODES) return;
  unsigned short* p = Xb + (size_t)row*HH + h0;
  union { unsigned short u[4]; uint2 d; } v;
  v.d = *(uint2*)p;
  float4 sc = *(const float4*)(scale + h0);
  float4 sh = *(const float4*)(shift + h0);
  v.u[0] = f2bf(elu(bf2f(v.u[0])*sc.x + sh.x));
  v.u[1] = f2bf(elu(bf2f(v.u[1])*sc.y + sh.y));
  v.u[2] = f2bf(elu(bf2f(v.u[2])*sc.z + sh.z));
  v.u[3] = f2bf(elu(bf2f(v.u[3])*sc.w + sh.w));
  *(uint2*)p = v.d;
}

// final BN+ELU: read bf16 Xb (raw layer-3 pre-BN), write fp32 d_out
__global__ __launch_bounds__(256) void bnout_kernel(
    const unsigned short* __restrict__ Xb, const float* __restrict__ scale,
    const float* __restrict__ shift, float* __restrict__ O) {
  int idx = blockIdx.x*256 + threadIdx.x;   // over MT*64
  int row = idx >> 6, h0 = (idx & 63)*4;
  int b = row >> 9, n = row & (NPAD-1);
  if (n >= NNODES) return;
  union { unsigned short u[4]; uint2 d; } v;
  v.d = *(const uint2*)(Xb + (size_t)row*HH + h0);
  float4 sc = *(const float4*)(scale + h0);
  float4 sh = *(const float4*)(shift + h0);
  float4 o;
  o.x = elu(bf2f(v.u[0])*sc.x + sh.x);
  o.y = elu(bf2f(v.u[1])*sc.y + sh.y);
  o.z = elu(bf2f(v.u[2])*sc.z + sh.z);
  o.w = elu(bf2f(v.u[3])*sc.w + sh.w);
  *(float4*)(O + ((size_t)(b*NNODES + n)*HH + h0)) = o;
}

extern "C" void kernel_launch(void* const* d_in, const int* in_sizes, int n_in,
                              void* d_out, int out_size, void* d_ws, size_t ws_size,
                              hipStream_t stream) {
  const float* sensor = (const float*)d_in[0];
  const float* base   = (const float*)d_in[1];
  const int*   eidx   = (const int*)d_in[2];
  const float* W1 = (const float*)d_in[3];
  const float* g1 = (const float*)d_in[5];
  const float* be1= (const float*)d_in[6];
  const float* W2 = (const float*)d_in[7];
  const float* g2 = (const float*)d_in[9];
  const float* be2= (const float*)d_in[10];
  const float* W3 = (const float*)d_in[11];
  const float* g3 = (const float*)d_in[13];
  const float* be3= (const float*)d_in[14];

  char* ws = (char*)d_ws;
  // ---- zeroed region [0, 16384) ----
  int*   deg    = (int*)(ws + 0);
  float* sum2   = (float*)(ws + 2048);
  float* ssq2   = (float*)(ws + 3072);
  float* sum3   = (float*)(ws + 4096);
  float* ssq3   = (float*)(ws + 5120);
  float* cbuf   = (float*)(ws + 6144);
  int*   cursor = (int*)(ws + 8192);
  int*   flag   = (int*)(ws + 10240);
  float* sA1    = (float*)(ws + 10496);
  float* sAA1   = (float*)(ws + 11520);
  float* sAc1   = (float*)(ws + 12544);
  float* scp    = (float*)(ws + 13568);
  float* ssA    = (float*)(ws + 13824);
  float* sssA   = (float*)(ws + 14848);
  // ---- end zeroed ----
  float* dinv   = (float*)(ws + 16384);
  int*   rp     = (int*)(ws + 18432);
  int*   colA   = (int*)(ws + 20480);
  float* valA   = (float*)(ws + 40960);
  float* scale1 = (float*)(ws + 61440);
  float* shift1 = (float*)(ws + 62464);
  float* scale2 = (float*)(ws + 63488);
  float* shift2 = (float*)(ws + 64512);
  float* scale3 = (float*)(ws + 65536);
  float* shift3 = (float*)(ws + 66560);
  float* Abuf   = (float*)(ws + 67584);                  // 502*256 f32
  float* hcat   = (float*)(ws + 581632);                 // 628*256 f32
  unsigned short* Wt2 = (unsigned short*)(ws + 1224704); // 256*256 bf16
  unsigned short* Wt3 = (unsigned short*)(ws + 1355776);
  unsigned short* Sd  = (unsigned short*)(ws + 1486848); // 512*512 bf16
  unsigned short* Xb  = (unsigned short*)(ws + 2011136); // MT*256 bf16
  unsigned short* Tt  = (unsigned short*)(ws + 35565568UL); // 256*MT bf16
  // Xp1/Wt1 alias the Tt region: only used before first gemmT writes Tt
  unsigned short* Xp1 = (unsigned short*)(ws + 35565568UL);            // 640*1024
  unsigned short* Wt1 = (unsigned short*)(ws + 35565568UL + 1310720);  // 256*1024
  float* out = (float*)d_out;
  float* Sdf = (float*)d_out;   // scratch; d_out rewritten by bnout at the end

  hipMemsetAsync(ws, 0, 16384, stream);
  hipMemsetAsync(d_out, 0, NPAD*NPAD*4, stream);
  detect_kernel<<<1, 256, 0, stream>>>(eidx, flag);
  deg_kernel<<<(NET+255)/256, 256, 0, stream>>>(eidx, flag, deg);
  scan_kernel<<<1, 512, 0, stream>>>(deg, dinv, rp, cursor);
  fill_kernel<<<(NET+255)/256, 256, 0, stream>>>(eidx, flag, dinv, cursor, colA, valA);
  sdf_kernel<<<(NET+255)/256, 256, 0, stream>>>(eidx, flag, dinv, Sdf);
  sdcvt_kernel<<<(NPAD*NPAD)/256, 256, 0, stream>>>(Sdf, Sd);
  prep_kernel<<<1408, 256, 0, stream>>>(W1, W2, W3, base, sensor, Wt1, Wt2, Wt3, Xp1);

  gemm1m_kernel<<<dim3(2, 5), 256, 0, stream>>>(Xp1, Wt1, hcat);
  ac_kernel<<<NNODES, 256, 0, stream>>>(rp, colA, valA, hcat, Abuf, cbuf);
  bn1n_kernel<<<40, 256, 0, stream>>>(Abuf, cbuf, hcat, sA1, sAA1, sAc1, scp, ssA, sssA);
  fin1_kernel<<<1, 256, 0, stream>>>(sA1, sAA1, sAc1, scp, ssA, sssA, g1, be1, scale1, shift1);
  x2_kernel<<<(MT*64)/256, 256, 0, stream>>>(Abuf, cbuf, hcat, scale1, shift1, Xb);

  gemmT_kernel<<<dim3(2, MT/128), 256, 0, stream>>>(Xb, Wt2, Tt);
  gemmS_kernel<<<1024, 256, 0, stream>>>(Sd, Tt, Xb, sum2, ssq2);
  finalize_kernel<<<1, 256, 0, stream>>>(sum2, ssq2, g2, be2, scale2, shift2);
  bnip_kernel<<<(MT*64)/256, 256, 0, stream>>>(Xb, scale2, shift2);

  gemmT_kernel<<<dim3(2, MT/128), 256, 0, stream>>>(Xb, Wt3, Tt);
  gemmS_kernel<<<1024, 256, 0, stream>>>(Sd, Tt, Xb, sum3, ssq3);
  finalize_kernel<<<1, 256, 0, stream>>>(sum3, ssq3, g3, be3, scale3, shift3);
  bnout_kernel<<<(MT*64)/256, 256, 0, stream>>>(Xb, scale3, shift3, out);
}